// Round 11
// baseline (393.368 us; speedup 1.0000x reference)
//
#include <hip/hip_runtime.h>
#include <math.h>

#define NSQ 1024
#define DM  512
#define HDIM 64
#define TOPK 32
#define QSTR 72   // LDS stride for staged Q (16B-aligned, conflict-free frags)
#define PCAP 64   // candidate buffer capacity per row (one per lane)

typedef unsigned short u16;
typedef __attribute__((ext_vector_type(8))) short bf16x8;
typedef __attribute__((ext_vector_type(4))) float f32x4;

#define MFMA_B16(A,B,C) __builtin_amdgcn_mfma_f32_16x16x32_bf16(A,B,C,0,0,0)

__device__ __forceinline__ unsigned f2b(float x) {
    unsigned u = __float_as_uint(x);
    return (u + 0x7FFFu + ((u >> 16) & 1u)) >> 16;   // RN-even to bf16 bits
}
__device__ __forceinline__ float b2f(unsigned h) { return __uint_as_float(h << 16); }
__device__ __forceinline__ unsigned ordu(float f) {
    unsigned b = __float_as_uint(f);
    return b ^ (0x80000000u | (unsigned)((int)b >> 31));  // order-preserving uint
}
__device__ __forceinline__ float iordu(unsigned u) {
    unsigned b = (u & 0x80000000u) ? (u ^ 0x80000000u) : ~u;
    return __uint_as_float(b);
}

// ---------------------------------------------------------------------------
// fp32 [8192x512] x2 -> bf16 hi/lo planes (tgt -> T*, src -> S*)
// ---------------------------------------------------------------------------
__global__ __launch_bounds__(256) void conv2(
    const float* __restrict__ tgt, const float* __restrict__ src,
    u16* __restrict__ Thi, u16* __restrict__ Tlo,
    u16* __restrict__ Shi, u16* __restrict__ Slo)
{
    const int z = blockIdx.y;
    const float* x = z ? src : tgt;
    u16* hi = z ? Shi : Thi;
    u16* lo = z ? Slo : Tlo;
    int idx = blockIdx.x * 256 + threadIdx.x;
    float4 v = ((const float4*)x)[idx];
    float f[4] = {v.x, v.y, v.z, v.w};
    ushort4 hv, lv;
    unsigned h;
    h = f2b(f[0]); hv.x = (u16)h; lv.x = (u16)f2b(f[0] - b2f(h));
    h = f2b(f[1]); hv.y = (u16)h; lv.y = (u16)f2b(f[1] - b2f(h));
    h = f2b(f[2]); hv.z = (u16)h; lv.z = (u16)f2b(f[2] - b2f(h));
    h = f2b(f[3]); hv.w = (u16)h; lv.w = (u16)f2b(f[3] - b2f(h));
    ((ushort4*)hi)[idx] = hv;
    ((ushort4*)lo)[idx] = lv;
}

// ---------------------------------------------------------------------------
// All 5 weights [512,512] -> transposed bf16 hi/lo planes, one dispatch.
// ---------------------------------------------------------------------------
__global__ __launch_bounds__(256) void wconv5(
    const float* __restrict__ Wq, const float* __restrict__ Wk,
    const float* __restrict__ Wv, const float* __restrict__ W1,
    const float* __restrict__ W2, u16* __restrict__ planes)
{
    __shared__ float T[32][33];
    const int wsel = blockIdx.z;
    const float* W = (wsel == 0) ? Wq : (wsel == 1) ? Wk : (wsel == 2) ? Wv
                   : (wsel == 3) ? W1 : W2;
    u16* thi = planes + (size_t)wsel * 2 * DM * DM;
    u16* tlo = thi + (size_t)DM * DM;
    const int tx = threadIdx.x & 31, ty = threadIdx.x >> 5;
    const int n0 = blockIdx.x * 32, k0 = blockIdx.y * 32;
#pragma unroll
    for (int p = 0; p < 4; ++p) {
        int r = ty + p * 8;
        T[r][tx] = W[(size_t)(k0 + r) * DM + n0 + tx];
    }
    __syncthreads();
#pragma unroll
    for (int p = 0; p < 4; ++p) {
        int rr = ty + p * 8;
        float val = T[tx][rr];                       // = W[k0+tx][n0+rr]
        unsigned h = f2b(val);
        size_t off = (size_t)(n0 + rr) * DM + k0 + tx;
        thi[off] = (u16)h;
        tlo[off] = (u16)f2b(val - b2f(h));
    }
}

// ---------------------------------------------------------------------------
// FUSED Q/K/V projection: one dispatch, grid (8, 64, 3). z selects
// {A-planes, B-planes, bias, scale, outputs}. All three use the 3-term
// split path (V gains the lo terms -> slightly MORE accurate than before).
// XCD-chunked swizzle: linear L = bx + by*8; XCD = bx owns A-rows
// [bx*1024, bx*1024+1024) x all 8 col-blocks -> per-XCD working set
// A-chunk 2MB + B 1MB < 4MB L2; each A row HBM-fetched by exactly one XCD.
// 128x64 tile, BK=64, 4 waves (2Mx2N), per-wave 64x32 via 4x2 frags.
// ---------------------------------------------------------------------------
__global__ __launch_bounds__(256, 4) void qkv512(
    const u16* __restrict__ Thi, const u16* __restrict__ Tlo,
    const u16* __restrict__ Shi, const u16* __restrict__ Slo,
    const u16* __restrict__ planes,
    const float* __restrict__ bq, const float* __restrict__ bk,
    const float* __restrict__ bv, float qscale,
    u16* __restrict__ qhi, u16* __restrict__ qlo,
    u16* __restrict__ khi, u16* __restrict__ klo,
    u16* __restrict__ vhi)
{
    __shared__ u16 Ah[128 * 72], Bh[64 * 72];
    __shared__ u16 Al[128 * 72], Bl[64 * 72];
    const int z = blockIdx.z;
    const size_t WPLANE = (size_t)DM * DM;
    const u16* Ah_g = z ? Shi : Thi;
    const u16* Al_g = z ? Slo : Tlo;
    const u16* Bh_g = planes + (size_t)z * 2 * WPLANE;
    const u16* Bl_g = Bh_g + WPLANE;
    const float* bias = (z == 0) ? bq : (z == 1) ? bk : bv;
    const float scale = (z == 0) ? qscale : 1.f;
    u16* oh = (z == 0) ? qhi : (z == 1) ? khi : vhi;
    u16* ol = (z == 0) ? qlo : (z == 1) ? klo : nullptr;

    const int tid = threadIdx.x, lane = tid & 63, w = tid >> 6;
    const int wr = (w >> 1) * 64, wc = (w & 1) * 32;
    const int ml = lane & 15, q8 = (lane >> 4) * 8, q4 = (lane >> 4) * 4;
    // XCD-chunk swizzle (dispatch-linear L = bx + by*8; z adds multiples of 8)
    const int bx = blockIdx.x, by = blockIdx.y;
    const int rb = (bx << 3) | (by >> 3);      // row-block 0..63
    const int cb = by & 7;                     // col-block 0..7
    const int row0 = rb * 128, col0 = cb * 64;
    const int sra = tid >> 1, sca = (tid & 1) * 32;   // A: 128 rows, 2 thr/row
    const int srb = tid >> 2, scb = (tid & 3) * 16;   // B: 64 rows, 4 thr/row

    f32x4 acc[4][2];
#pragma unroll
    for (int i = 0; i < 4; ++i)
#pragma unroll
        for (int j = 0; j < 2; ++j) acc[i][j] = {0.f, 0.f, 0.f, 0.f};

    for (int k0 = 0; k0 < DM; k0 += 64) {
        const size_t ra = (size_t)(row0 + sra) * DM + k0 + sca;
        const size_t rbo = (size_t)(col0 + srb) * DM + k0 + scb;
#pragma unroll
        for (int u = 0; u < 4; ++u) {
            *(uint4*)&Ah[sra * 72 + sca + u * 8] = *(const uint4*)&Ah_g[ra + u * 8];
            *(uint4*)&Al[sra * 72 + sca + u * 8] = *(const uint4*)&Al_g[ra + u * 8];
        }
#pragma unroll
        for (int u = 0; u < 2; ++u) {
            *(uint4*)&Bh[srb * 72 + scb + u * 8] = *(const uint4*)&Bh_g[rbo + u * 8];
            *(uint4*)&Bl[srb * 72 + scb + u * 8] = *(const uint4*)&Bl_g[rbo + u * 8];
        }
        __syncthreads();
#pragma unroll
        for (int kk = 0; kk < 64; kk += 32) {
            bf16x8 a_h[4], b_h[2], a_l[4], b_l[2];
#pragma unroll
            for (int i = 0; i < 4; ++i) {
                a_h[i] = *(const bf16x8*)&Ah[(wr + i * 16 + ml) * 72 + kk + q8];
                a_l[i] = *(const bf16x8*)&Al[(wr + i * 16 + ml) * 72 + kk + q8];
            }
#pragma unroll
            for (int j = 0; j < 2; ++j) {
                b_h[j] = *(const bf16x8*)&Bh[(wc + j * 16 + ml) * 72 + kk + q8];
                b_l[j] = *(const bf16x8*)&Bl[(wc + j * 16 + ml) * 72 + kk + q8];
            }
#pragma unroll
            for (int i = 0; i < 4; ++i)
#pragma unroll
                for (int j = 0; j < 2; ++j) {
                    acc[i][j] = MFMA_B16(a_h[i], b_h[j], acc[i][j]);
                    acc[i][j] = MFMA_B16(a_h[i], b_l[j], acc[i][j]);
                    acc[i][j] = MFMA_B16(a_l[i], b_h[j], acc[i][j]);
                    // lo*lo dropped: ~2^-18 relative contribution
                }
        }
        __syncthreads();
    }

    float bcol[2];
#pragma unroll
    for (int j = 0; j < 2; ++j) bcol[j] = bias[col0 + wc + j * 16 + ml];
#pragma unroll
    for (int i = 0; i < 4; ++i)
#pragma unroll
        for (int j = 0; j < 2; ++j)
#pragma unroll
            for (int r = 0; r < 4; ++r) {
                int gm = row0 + wr + i * 16 + q4 + r;
                int gn = col0 + wc + j * 16 + ml;
                float t = (acc[i][j][r] + bcol[j]) * scale;
                size_t off = (size_t)gm * DM + gn;
                unsigned hb2 = f2b(t);
                oh[off] = (u16)hb2;
                if (ol) ol[off] = (u16)f2b(t - b2f(hb2));
            }
}

// ---------------------------------------------------------------------------
// C[8192,512] = act(A @ B^T + bias)*scale (+R) -- FF path (non-split A).
// 128x64 tile, grid (8, 64) with the same XCD-chunk swizzle as qkv512.
// OUTMODE: 0 = fp32 (+R), 2 = bf16 hi only.
// ---------------------------------------------------------------------------
template<int RELU, int OUTMODE>
__global__ __launch_bounds__(256, 4) void mm512(
    const u16* __restrict__ Ah_g, const u16* __restrict__ Bh_g,
    const float* __restrict__ bias, const float* __restrict__ R,
    float scale, float* __restrict__ outF, u16* __restrict__ outHi)
{
    __shared__ u16 Ah[128 * 72], Bh[64 * 72];
    const int tid = threadIdx.x, lane = tid & 63, w = tid >> 6;
    const int wr = (w >> 1) * 64, wc = (w & 1) * 32;
    const int ml = lane & 15, q8 = (lane >> 4) * 8, q4 = (lane >> 4) * 4;
    const int bx = blockIdx.x, by = blockIdx.y;
    const int rb = (bx << 3) | (by >> 3);
    const int cb = by & 7;
    const int row0 = rb * 128, col0 = cb * 64;
    const int sra = tid >> 1, sca = (tid & 1) * 32;
    const int srb = tid >> 2, scb = (tid & 3) * 16;

    f32x4 acc[4][2];
#pragma unroll
    for (int i = 0; i < 4; ++i)
#pragma unroll
        for (int j = 0; j < 2; ++j) acc[i][j] = {0.f, 0.f, 0.f, 0.f};

    for (int k0 = 0; k0 < DM; k0 += 64) {
        const size_t ra = (size_t)(row0 + sra) * DM + k0 + sca;
        const size_t rbo = (size_t)(col0 + srb) * DM + k0 + scb;
#pragma unroll
        for (int u = 0; u < 4; ++u)
            *(uint4*)&Ah[sra * 72 + sca + u * 8] = *(const uint4*)&Ah_g[ra + u * 8];
#pragma unroll
        for (int u = 0; u < 2; ++u)
            *(uint4*)&Bh[srb * 72 + scb + u * 8] = *(const uint4*)&Bh_g[rbo + u * 8];
        __syncthreads();
#pragma unroll
        for (int kk = 0; kk < 64; kk += 32) {
            bf16x8 a_h[4], b_h[2];
#pragma unroll
            for (int i = 0; i < 4; ++i)
                a_h[i] = *(const bf16x8*)&Ah[(wr + i * 16 + ml) * 72 + kk + q8];
#pragma unroll
            for (int j = 0; j < 2; ++j)
                b_h[j] = *(const bf16x8*)&Bh[(wc + j * 16 + ml) * 72 + kk + q8];
#pragma unroll
            for (int i = 0; i < 4; ++i)
#pragma unroll
                for (int j = 0; j < 2; ++j)
                    acc[i][j] = MFMA_B16(a_h[i], b_h[j], acc[i][j]);
        }
        __syncthreads();
    }

    float bcol[2];
#pragma unroll
    for (int j = 0; j < 2; ++j) bcol[j] = bias[col0 + wc + j * 16 + ml];
#pragma unroll
    for (int i = 0; i < 4; ++i)
#pragma unroll
        for (int j = 0; j < 2; ++j)
#pragma unroll
            for (int r = 0; r < 4; ++r) {
                int gm = row0 + wr + i * 16 + q4 + r;
                int gn = col0 + wc + j * 16 + ml;
                float t = acc[i][j][r] + bcol[j];
                if (RELU) t = fmaxf(t, 0.f);
                t *= scale;
                size_t off = (size_t)gm * DM + gn;
                if (OUTMODE == 0) {
                    if (R) t += R[off];
                    outF[off] = t;
                } else {
                    outHi[off] = (u16)f2b(t);
                }
            }
}

// ---------------------------------------------------------------------------
// FUSED attention middle, v9 = v7 + XCD-aware block swizzle (measured:
// FETCH 105->20.6MB, dur ~200.5us; latency/instruction-bound, kept for the
// traffic win). 512-thread blocks (8 waves), acc[8]/lane, (512,4).
// ---------------------------------------------------------------------------
__global__ __launch_bounds__(512, 4) void attn_fused(
    const u16* __restrict__ qhi, const u16* __restrict__ qlo,
    const u16* __restrict__ khi, const u16* __restrict__ klo,
    const u16* __restrict__ vhi, u16* __restrict__ ao)
{
    __shared__ u16 Qh[16 * QSTR], Ql[16 * QSTR];
    __shared__ float statS[8][16], statQ[8][16];
    __shared__ int   cntW[2][8][16];
    __shared__ float2 pbuf[16 * PCAP];
    __shared__ int   pcnt[16];
    __shared__ unsigned loU[16], hiU[16];

    const int tid = threadIdx.x, lane = tid & 63, w = tid >> 6;   // w in 0..7
    const int ml = lane & 15, quad = lane >> 4, q8 = quad * 8;
    // XCD swizzle: L = x + y*64 dispatch-linear; xcd = L&7 owns batch b=xcd.
    const int L = blockIdx.x + (blockIdx.y << 6);
    const int slot = L >> 3;
    const int hb = ((slot >> 6) << 3) | (L & 7);   // h = slot>>6, b = L&7
    const int h = hb >> 3, b = hb & 7;
    const int r0 = (slot & 63) << 4;

    // ---- stage Q (16 rows x 64 dims, hi+lo planes) ----
    if (tid < 256) {
        int t2 = tid & 127, m = t2 >> 3, k8 = (t2 & 7) * 8;
        const u16* sp = (tid < 128) ? qhi : qlo;
        u16* dst = (tid < 128) ? Qh : Ql;
        *(uint4*)&dst[m * QSTR + k8] =
            *(const uint4*)&sp[((size_t)(b * NSQ + r0 + m)) * DM + h * HDIM + k8];
    }
    if (tid < 16) pcnt[tid] = 0;
    __syncthreads();

    bf16x8 a_h0 = *(const bf16x8*)&Qh[ml * QSTR + q8];
    bf16x8 a_h1 = *(const bf16x8*)&Qh[ml * QSTR + 32 + q8];
    bf16x8 a_l0 = *(const bf16x8*)&Ql[ml * QSTR + q8];
    bf16x8 a_l1 = *(const bf16x8*)&Ql[ml * QSTR + 32 + q8];

    // ---- phase 1: scores into registers (wave w owns cols w*128..w*128+127)
    const u16* khp = khi + ((size_t)(b * NSQ + w * 128 + ml)) * DM + h * HDIM + q8;
    const u16* klp = klo + ((size_t)(b * NSQ + w * 128 + ml)) * DM + h * HDIM + q8;

    f32x4 acc[8];
#pragma unroll
    for (int t = 0; t < 8; ++t) {
        bf16x8 bh0 = *(const bf16x8*)(khp);
        bf16x8 bh1 = *(const bf16x8*)(khp + 32);
        bf16x8 bl0 = *(const bf16x8*)(klp);
        bf16x8 bl1 = *(const bf16x8*)(klp + 32);
        f32x4 a0 = {0.f, 0.f, 0.f, 0.f}, a1 = {0.f, 0.f, 0.f, 0.f};
        a0 = MFMA_B16(a_h0, bh0, a0);
        a0 = MFMA_B16(a_h1, bh1, a0);
        a0 = MFMA_B16(a_l0, bh0, a0);
        a0 = MFMA_B16(a_l1, bh1, a0);
        a1 = MFMA_B16(a_h0, bl0, a1);
        a1 = MFMA_B16(a_h1, bl1, a1);
        a1 = MFMA_B16(a_l0, bl0, a1);
        a1 = MFMA_B16(a_l1, bl1, a1);
        acc[t] = a0 + a1;
        khp += 16 * DM;
        klp += 16 * DM;
    }
    // acc[t][r] = S[row = quad*4 + r][col = w*128 + t*16 + ml]

    // ---- stats: mu/sigma per row ----
    float s1[4] = {0.f, 0.f, 0.f, 0.f}, s2[4] = {0.f, 0.f, 0.f, 0.f};
#pragma unroll
    for (int t = 0; t < 8; ++t)
#pragma unroll
        for (int r = 0; r < 4; ++r) {
            float v = acc[t][r];
            s1[r] += v;
            s2[r] = fmaf(v, v, s2[r]);
        }
#pragma unroll
    for (int off = 8; off; off >>= 1)
#pragma unroll
        for (int r = 0; r < 4; ++r) {
            s1[r] += __shfl_xor(s1[r], off);
            s2[r] += __shfl_xor(s2[r], off);
        }
    if (ml == 0)
#pragma unroll
        for (int r = 0; r < 4; ++r) {
            statS[w][quad * 4 + r] = s1[r];
            statQ[w][quad * 4 + r] = s2[r];
        }
    __syncthreads();

    // count helper: threshold-compare local scores, block-reduce via LDS.
    // (barriers are unconditional -> no divergent sync)
    auto probe_count = [&](const float* thr, int buf, int* tot) {
        int c[4] = {0, 0, 0, 0};
#pragma unroll
        for (int t = 0; t < 8; ++t)
#pragma unroll
            for (int r = 0; r < 4; ++r) c[r] += (acc[t][r] > thr[r]) ? 1 : 0;
#pragma unroll
        for (int off = 8; off; off >>= 1)
#pragma unroll
            for (int r = 0; r < 4; ++r) c[r] += __shfl_xor(c[r], off);
        if (ml == 0)
#pragma unroll
            for (int r = 0; r < 4; ++r) cntW[buf][w][quad * 4 + r] = c[r];
        __syncthreads();
#pragma unroll
        for (int r = 0; r < 4; ++r) {
            int row = quad * 4 + r;
            int tt = 0;
#pragma unroll
            for (int i = 0; i < 8; ++i) tt += cntW[buf][i][row];
            tot[r] = tt;
        }
    };

    unsigned lo_u[4], hi_u[4];
    int done = 0;
    {   // ---- peeled seeded probes (mu/sg die here, before the loop) ----
        float mu[4], sg[4];
#pragma unroll
        for (int r = 0; r < 4; ++r) {
            int row = quad * 4 + r;
            float S = 0.f, Q = 0.f;
#pragma unroll
            for (int i = 0; i < 8; ++i) { S += statS[i][row]; Q += statQ[i][row]; }
            mu[r] = S * (1.f / 1024.f);
            sg[r] = sqrtf(fmaxf(Q * (1.f / 1024.f) - mu[r] * mu[r], 0.f)) + 1e-20f;
            // Chebyshev: #{x >= mu+8s} <= 16 < 32 and #{x <= mu-8s} <= 16
            lo_u[r] = ordu(mu[r] - 8.f * sg[r]);
            hi_u[r] = ordu(mu[r] + 8.f * sg[r]);
        }
        // probe A: mu + 1.70 sg
        bool below[4];
        {
            float thr[4]; unsigned tu[4]; int tot[4];
#pragma unroll
            for (int r = 0; r < 4; ++r) { thr[r] = mu[r] + 1.70f * sg[r]; tu[r] = ordu(thr[r]); }
            probe_count(thr, 0, tot);
#pragma unroll
            for (int r = 0; r < 4; ++r) {
                below[r] = (tot[r] < TOPK);
                if (tot[r] >= TOPK) {
                    lo_u[r] = tu[r];
                    if (tot[r] <= PCAP) done |= 1 << r;
                } else hi_u[r] = tu[r];
                if (hi_u[r] - lo_u[r] <= 1u) done |= 1 << r;
            }
        }
        // probe B: mu + (below ? 1.38 : 2.15) sg, clamped into (lo,hi)
        {
            float thr[4]; unsigned tu[4]; int tot[4];
#pragma unroll
            for (int r = 0; r < 4; ++r) {
                if (!((done >> r) & 1)) {
                    float fr = mu[r] + (below[r] ? 1.38f : 2.15f) * sg[r];
                    unsigned um = ordu(fr);
                    if (um <= lo_u[r] || um >= hi_u[r]) {
                        um = lo_u[r] + ((hi_u[r] - lo_u[r]) >> 1);
                        fr = iordu(um);
                    }
                    thr[r] = fr; tu[r] = um;
                } else { tu[r] = lo_u[r]; thr[r] = iordu(lo_u[r]); }
            }
            probe_count(thr, 1, tot);
#pragma unroll
            for (int r = 0; r < 4; ++r) {
                if (!((done >> r) & 1)) {
                    if (tot[r] >= TOPK) {
                        lo_u[r] = tu[r];
                        if (tot[r] <= PCAP) done |= 1 << r;
                    } else hi_u[r] = tu[r];
                    if (hi_u[r] - lo_u[r] <= 1u) done |= 1 << r;
                }
            }
        }
    }

    // ---- uint bisect loop: only lo_u/hi_u carried ----
    for (int iter = 0; iter < 22; ++iter) {
        if (__all(done == 15)) break;
        float thr[4]; unsigned tu[4]; int tot[4];
#pragma unroll
        for (int r = 0; r < 4; ++r) {
            unsigned um = ((done >> r) & 1) ? lo_u[r]
                        : lo_u[r] + ((hi_u[r] - lo_u[r]) >> 1);
            tu[r] = um; thr[r] = iordu(um);
        }
        probe_count(thr, iter & 1, tot);
#pragma unroll
        for (int r = 0; r < 4; ++r) {
            if (!((done >> r) & 1)) {
                if (tot[r] >= TOPK) {
                    lo_u[r] = tu[r];
                    if (tot[r] <= PCAP) done |= 1 << r;    // window hit
                } else hi_u[r] = tu[r];
                if (hi_u[r] - lo_u[r] <= 1u) done |= 1 << r;
            }
        }
    }

    if (w == 0 && ml == 0)
#pragma unroll
        for (int r = 0; r < 4; ++r) {
            loU[quad * 4 + r] = lo_u[r];
            hiU[quad * 4 + r] = hi_u[r];
        }

    // ---- extraction: LDS atomic append (slot order irrelevant) ----
    {
        float lof[4];
#pragma unroll
        for (int r = 0; r < 4; ++r) lof[r] = iordu(lo_u[r]);
#pragma unroll
        for (int t = 0; t < 8; ++t)
#pragma unroll
            for (int r = 0; r < 4; ++r) {
                if (acc[t][r] > lof[r]) {
                    int row = quad * 4 + r;
                    int s = atomicAdd(&pcnt[row], 1);
                    if (s < PCAP)
                        pbuf[row * PCAP + s] =
                            make_float2(acc[t][r], __int_as_float(w * 128 + t * 16 + ml));
                }
            }
    }
    __syncthreads();

    // ---- finale per wave (rows w*2, w*2+1): micro-bisect to exact 32,
    //      tie-prune, softmax (threshold shift), compact, batched PV.
    const u16* vb = vhi + ((size_t)b * NSQ) * DM + h * HDIM + lane;
    for (int rr = 0; rr < 2; ++rr) {
        const int row = w * 2 + rr;
        int n = pcnt[row];
        if (n > PCAP) n = PCAP;
        float2 pr = (lane < n) ? pbuf[row * PCAP + lane] : make_float2(0.f, 0.f);
        float val = pr.x;
        int   col = __float_as_int(pr.y);
        unsigned uv = (lane < n) ? ordu(val) : 0u;

        // micro-bisect: value-space midpoints (uint fallback alternating)
        unsigned blo = loU[row], bhi = hiU[row];
        int it = 0;
        while (bhi - blo > 1u) {
            unsigned um;
            if (it & 1) um = blo + ((bhi - blo) >> 1);
            else {
                um = ordu(0.5f * (iordu(blo) + iordu(bhi)));
                if (um <= blo || um >= bhi) um = blo + ((bhi - blo) >> 1);
            }
            ++it;
            int c = __popcll(__ballot(uv > um));
            if (c >= TOPK) { blo = um; if (c == TOPK) break; }
            else bhi = um;
        }
        bool sel = uv > blo;
        int excess = __popcll(__ballot(sel)) - TOPK;
        while (excess > 0) {        // ties at boundary (rare): drop largest cols
            int mycol = (sel && uv == blo + 1u) ? col : -1;
            int cmx = mycol;
#pragma unroll
            for (int off = 32; off; off >>= 1) cmx = max(cmx, __shfl_xor(cmx, off));
            if (sel && mycol >= 0 && col == cmx) sel = false;
            excess--;
        }

        // softmax with threshold shift (mathematically identical to max-shift)
        float mshift = iordu(blo);
        float e = sel ? __expf(val - mshift) : 0.f;
        float s = e;
#pragma unroll
        for (int off = 32; off; off >>= 1) s += __shfl_xor(s, off);
        float p = e * (1.f / s);

        // compact selected 32 to slots 0..31 (wave-local; lgkm orders wr->rd)
        unsigned long long bm = __ballot(sel);
        int slot2 = __popcll(bm & ((1ull << lane) - 1ull));
        if (sel) pbuf[row * PCAP + slot2] = make_float2(p, __int_as_float(col));

        float accv = 0.f;
#pragma unroll
        for (int t0 = 0; t0 < TOPK; t0 += 16) {
            float pp[16]; int cc[16]; u16 vv[16];
#pragma unroll
            for (int j = 0; j < 16; ++j) {
                float2 pc = pbuf[row * PCAP + t0 + j];
                pp[j] = pc.x; cc[j] = __float_as_int(pc.y);
            }
#pragma unroll
            for (int j = 0; j < 16; ++j) vv[j] = vb[(size_t)cc[j] * DM];
#pragma unroll
            for (int j = 0; j < 16; ++j) accv = fmaf(pp[j], b2f(vv[j]), accv);
        }
        ao[((size_t)(b * NSQ + r0 + row)) * DM + h * HDIM + lane] = (u16)f2b(accv);
    }
}

// ---------------------------------------------------------------------------
// LayerNorm: out = LN(a [+ bf16 addb]) * g + be; optional fp32 + bf16-hi outs
// ---------------------------------------------------------------------------
__global__ __launch_bounds__(256) void ln_fused(
    const float* __restrict__ a, const u16* __restrict__ addb,
    const float* __restrict__ g, const float* __restrict__ be,
    float* __restrict__ outF, u16* __restrict__ outHi)
{
    __shared__ float red[4][2];
    const int row = blockIdx.x, tid = threadIdx.x, w = tid >> 6;
    float2 v = ((const float2*)(a + (size_t)row * DM))[tid];
    if (addb) {
        ushort2 ab = ((const ushort2*)(addb + (size_t)row * DM))[tid];
        v.x += b2f(ab.x); v.y += b2f(ab.y);
    }
    float s = v.x + v.y, q = v.x * v.x + v.y * v.y;
#pragma unroll
    for (int o = 32; o; o >>= 1) { s += __shfl_xor(s, o); q += __shfl_xor(q, o); }
    if ((tid & 63) == 0) { red[w][0] = s; red[w][1] = q; }
    __syncthreads();
    float S = red[0][0] + red[1][0] + red[2][0] + red[3][0];
    float Q = red[0][1] + red[1][1] + red[2][1] + red[3][1];
    float mu = S * (1.f / DM);
    float var = Q * (1.f / DM) - mu * mu;
    float rs = rsqrtf(var + 1e-5f);
    float2 gv = ((const float2*)g)[tid];
    float2 bv = ((const float2*)be)[tid];
    float2 o;
    o.x = (v.x - mu) * rs * gv.x + bv.x;
    o.y = (v.y - mu) * rs * gv.y + bv.y;
    if (outF) ((float2*)(outF + (size_t)row * DM))[tid] = o;
    if (outHi) {
        ushort2 hv; hv.x = (u16)f2b(o.x); hv.y = (u16)f2b(o.y);
        ((ushort2*)(outHi + (size_t)row * DM))[tid] = hv;
    }
}

// ---------------------------------------------------------------------------
extern "C" void kernel_launch(void* const* d_in, const int* in_sizes, int n_in,
                              void* d_out, int out_size, void* d_ws, size_t ws_size,
                              hipStream_t stream) {
    const float* src = (const float*)d_in[0];
    const float* tgt = (const float*)d_in[1];
    const float* Wq  = (const float*)d_in[2];
    const float* bq  = (const float*)d_in[3];
    const float* Wk  = (const float*)d_in[4];
    const float* bk  = (const float*)d_in[5];
    const float* Wv  = (const float*)d_in[6];
    const float* bv  = (const float*)d_in[7];
    const float* W1  = (const float*)d_in[8];
    const float* b1  = (const float*)d_in[9];
    const float* W2  = (const float*)d_in[10];
    const float* b2  = (const float*)d_in[11];
    const float* g1  = (const float*)d_in[12];
    const float* be1 = (const float*)d_in[13];
    const float* g2  = (const float*)d_in[14];
    const float* be2 = (const float*)d_in[15];

    // workspace map (MB offsets). Total footprint: 136 MB.
    const size_t WPLANE = (size_t)DM * DM;
    u16* planes = (u16*)d_ws;                    // 10 x 512 KB = 5 MB
    auto wh = [&](int i) { return planes + (size_t)i * 2 * WPLANE; };
    auto at = [&](size_t mb) { return (char*)d_ws + (mb << 20); };
    u16* Thi = (u16*)at(8);   u16* Tlo = (u16*)at(16);
    u16* Shi = (u16*)at(24);  u16* Slo = (u16*)at(32);
    u16* qhi = (u16*)at(40);  u16* qlo = (u16*)at(48);
    u16* khi = (u16*)at(56);  u16* klo = (u16*)at(64);
    u16* vhi = (u16*)at(72);
    u16* aob = (u16*)at(80);
    float* xb = (float*)at(88);                  // 16 MB fp32
    u16* xhi = (u16*)at(104);
    u16* hhi = (u16*)at(112);
    float* f2 = (float*)at(120);                 // 16 MB fp32

    dim3 blk(256);
    const float qscale = 0.04419417382415922f;   // 1/sqrt(512)

    wconv5<<<dim3(16, 16, 5), blk, 0, stream>>>(Wq, Wk, Wv, W1, W2, planes);
    conv2<<<dim3(4096, 2), blk, 0, stream>>>(tgt, src, Thi, Tlo, Shi, Slo);

    // fused Q/K/V projection: one dispatch, 1536 blocks
    qkv512<<<dim3(8, 64, 3), blk, 0, stream>>>(Thi, Tlo, Shi, Slo, planes,
                                               bq, bk, bv, qscale,
                                               qhi, qlo, khi, klo, vhi);

    attn_fused<<<dim3(64, 64), dim3(512), 0, stream>>>(qhi, qlo, khi, klo, vhi, aob);

    ln_fused<<<8192, blk, 0, stream>>>(tgt, aob, g1, be1, xb, xhi);
    mm512<1, 2><<<dim3(8, 64), blk, 0, stream>>>(xhi, wh(3), b1, nullptr,
                                                 1.f, nullptr, hhi);
    mm512<0, 0><<<dim3(8, 64), blk, 0, stream>>>(hhi, wh(4), b2, xb,
                                                 1.f, f2, nullptr);
    ln_fused<<<8192, blk, 0, stream>>>(f2, nullptr, g2, be2, (float*)d_out, nullptr);
}

// Round 12
// 386.351 us; speedup vs baseline: 1.0182x; 1.0182x over previous
//
#include <hip/hip_runtime.h>
#include <math.h>

#define NSQ 1024
#define DM  512
#define HDIM 64
#define TOPK 32
#define QSTR 72   // LDS stride for staged Q (16B-aligned, conflict-free frags)
#define PCAP 64   // candidate buffer capacity per row (one per lane)

typedef unsigned short u16;
typedef __attribute__((ext_vector_type(8))) short bf16x8;
typedef __attribute__((ext_vector_type(4))) float f32x4;

#define MFMA_B16(A,B,C) __builtin_amdgcn_mfma_f32_16x16x32_bf16(A,B,C,0,0,0)

__device__ __forceinline__ unsigned f2b(float x) {
    unsigned u = __float_as_uint(x);
    return (u + 0x7FFFu + ((u >> 16) & 1u)) >> 16;   // RN-even to bf16 bits
}
__device__ __forceinline__ float b2f(unsigned h) { return __uint_as_float(h << 16); }
__device__ __forceinline__ unsigned ordu(float f) {
    unsigned b = __float_as_uint(f);
    return b ^ (0x80000000u | (unsigned)((int)b >> 31));  // order-preserving uint
}
__device__ __forceinline__ float iordu(unsigned u) {
    unsigned b = (u & 0x80000000u) ? (u ^ 0x80000000u) : ~u;
    return __uint_as_float(b);
}

// ---------------------------------------------------------------------------
// fp32 [8192x512] x2 -> bf16 hi/lo planes (tgt -> T*, src -> S*)
// ---------------------------------------------------------------------------
__global__ __launch_bounds__(256) void conv2(
    const float* __restrict__ tgt, const float* __restrict__ src,
    u16* __restrict__ Thi, u16* __restrict__ Tlo,
    u16* __restrict__ Shi, u16* __restrict__ Slo)
{
    const int z = blockIdx.y;
    const float* x = z ? src : tgt;
    u16* hi = z ? Shi : Thi;
    u16* lo = z ? Slo : Tlo;
    int idx = blockIdx.x * 256 + threadIdx.x;
    float4 v = ((const float4*)x)[idx];
    float f[4] = {v.x, v.y, v.z, v.w};
    ushort4 hv, lv;
    unsigned h;
    h = f2b(f[0]); hv.x = (u16)h; lv.x = (u16)f2b(f[0] - b2f(h));
    h = f2b(f[1]); hv.y = (u16)h; lv.y = (u16)f2b(f[1] - b2f(h));
    h = f2b(f[2]); hv.z = (u16)h; lv.z = (u16)f2b(f[2] - b2f(h));
    h = f2b(f[3]); hv.w = (u16)h; lv.w = (u16)f2b(f[3] - b2f(h));
    ((ushort4*)hi)[idx] = hv;
    ((ushort4*)lo)[idx] = lv;
}

// ---------------------------------------------------------------------------
// All 5 weights [512,512] -> transposed bf16 hi/lo planes, one dispatch.
// ---------------------------------------------------------------------------
__global__ __launch_bounds__(256) void wconv5(
    const float* __restrict__ Wq, const float* __restrict__ Wk,
    const float* __restrict__ Wv, const float* __restrict__ W1,
    const float* __restrict__ W2, u16* __restrict__ planes)
{
    __shared__ float T[32][33];
    const int wsel = blockIdx.z;
    const float* W = (wsel == 0) ? Wq : (wsel == 1) ? Wk : (wsel == 2) ? Wv
                   : (wsel == 3) ? W1 : W2;
    u16* thi = planes + (size_t)wsel * 2 * DM * DM;
    u16* tlo = thi + (size_t)DM * DM;
    const int tx = threadIdx.x & 31, ty = threadIdx.x >> 5;
    const int n0 = blockIdx.x * 32, k0 = blockIdx.y * 32;
#pragma unroll
    for (int p = 0; p < 4; ++p) {
        int r = ty + p * 8;
        T[r][tx] = W[(size_t)(k0 + r) * DM + n0 + tx];
    }
    __syncthreads();
#pragma unroll
    for (int p = 0; p < 4; ++p) {
        int rr = ty + p * 8;
        float val = T[tx][rr];                       // = W[k0+tx][n0+rr]
        unsigned h = f2b(val);
        size_t off = (size_t)(n0 + rr) * DM + k0 + tx;
        thi[off] = (u16)h;
        tlo[off] = (u16)f2b(val - b2f(h));
    }
}

// ---------------------------------------------------------------------------
// FUSED Q/K/V projection: one dispatch, grid (8, 64, 3). z selects
// {A-planes, B-planes, bias, scale, outputs}. All three use the 3-term
// split path. XCD-chunked swizzle. 128x64 tile, BK=64, 4 waves (2Mx2N).
// ---------------------------------------------------------------------------
__global__ __launch_bounds__(256, 4) void qkv512(
    const u16* __restrict__ Thi, const u16* __restrict__ Tlo,
    const u16* __restrict__ Shi, const u16* __restrict__ Slo,
    const u16* __restrict__ planes,
    const float* __restrict__ bq, const float* __restrict__ bk,
    const float* __restrict__ bv, float qscale,
    u16* __restrict__ qhi, u16* __restrict__ qlo,
    u16* __restrict__ khi, u16* __restrict__ klo,
    u16* __restrict__ vhi)
{
    __shared__ u16 Ah[128 * 72], Bh[64 * 72];
    __shared__ u16 Al[128 * 72], Bl[64 * 72];
    const int z = blockIdx.z;
    const size_t WPLANE = (size_t)DM * DM;
    const u16* Ah_g = z ? Shi : Thi;
    const u16* Al_g = z ? Slo : Tlo;
    const u16* Bh_g = planes + (size_t)z * 2 * WPLANE;
    const u16* Bl_g = Bh_g + WPLANE;
    const float* bias = (z == 0) ? bq : (z == 1) ? bk : bv;
    const float scale = (z == 0) ? qscale : 1.f;
    u16* oh = (z == 0) ? qhi : (z == 1) ? khi : vhi;
    u16* ol = (z == 0) ? qlo : (z == 1) ? klo : nullptr;

    const int tid = threadIdx.x, lane = tid & 63, w = tid >> 6;
    const int wr = (w >> 1) * 64, wc = (w & 1) * 32;
    const int ml = lane & 15, q8 = (lane >> 4) * 8, q4 = (lane >> 4) * 4;
    const int bx = blockIdx.x, by = blockIdx.y;
    const int rb = (bx << 3) | (by >> 3);      // row-block 0..63
    const int cb = by & 7;                     // col-block 0..7
    const int row0 = rb * 128, col0 = cb * 64;
    const int sra = tid >> 1, sca = (tid & 1) * 32;   // A: 128 rows, 2 thr/row
    const int srb = tid >> 2, scb = (tid & 3) * 16;   // B: 64 rows, 4 thr/row

    f32x4 acc[4][2];
#pragma unroll
    for (int i = 0; i < 4; ++i)
#pragma unroll
        for (int j = 0; j < 2; ++j) acc[i][j] = {0.f, 0.f, 0.f, 0.f};

    for (int k0 = 0; k0 < DM; k0 += 64) {
        const size_t ra = (size_t)(row0 + sra) * DM + k0 + sca;
        const size_t rbo = (size_t)(col0 + srb) * DM + k0 + scb;
#pragma unroll
        for (int u = 0; u < 4; ++u) {
            *(uint4*)&Ah[sra * 72 + sca + u * 8] = *(const uint4*)&Ah_g[ra + u * 8];
            *(uint4*)&Al[sra * 72 + sca + u * 8] = *(const uint4*)&Al_g[ra + u * 8];
        }
#pragma unroll
        for (int u = 0; u < 2; ++u) {
            *(uint4*)&Bh[srb * 72 + scb + u * 8] = *(const uint4*)&Bh_g[rbo + u * 8];
            *(uint4*)&Bl[srb * 72 + scb + u * 8] = *(const uint4*)&Bl_g[rbo + u * 8];
        }
        __syncthreads();
#pragma unroll
        for (int kk = 0; kk < 64; kk += 32) {
            bf16x8 a_h[4], b_h[2], a_l[4], b_l[2];
#pragma unroll
            for (int i = 0; i < 4; ++i) {
                a_h[i] = *(const bf16x8*)&Ah[(wr + i * 16 + ml) * 72 + kk + q8];
                a_l[i] = *(const bf16x8*)&Al[(wr + i * 16 + ml) * 72 + kk + q8];
            }
#pragma unroll
            for (int j = 0; j < 2; ++j) {
                b_h[j] = *(const bf16x8*)&Bh[(wc + j * 16 + ml) * 72 + kk + q8];
                b_l[j] = *(const bf16x8*)&Bl[(wc + j * 16 + ml) * 72 + kk + q8];
            }
#pragma unroll
            for (int i = 0; i < 4; ++i)
#pragma unroll
                for (int j = 0; j < 2; ++j) {
                    acc[i][j] = MFMA_B16(a_h[i], b_h[j], acc[i][j]);
                    acc[i][j] = MFMA_B16(a_h[i], b_l[j], acc[i][j]);
                    acc[i][j] = MFMA_B16(a_l[i], b_h[j], acc[i][j]);
                    // lo*lo dropped: ~2^-18 relative contribution
                }
        }
        __syncthreads();
    }

    float bcol[2];
#pragma unroll
    for (int j = 0; j < 2; ++j) bcol[j] = bias[col0 + wc + j * 16 + ml];
#pragma unroll
    for (int i = 0; i < 4; ++i)
#pragma unroll
        for (int j = 0; j < 2; ++j)
#pragma unroll
            for (int r = 0; r < 4; ++r) {
                int gm = row0 + wr + i * 16 + q4 + r;
                int gn = col0 + wc + j * 16 + ml;
                float t = (acc[i][j][r] + bcol[j]) * scale;
                size_t off = (size_t)gm * DM + gn;
                unsigned hb2 = f2b(t);
                oh[off] = (u16)hb2;
                if (ol) ol[off] = (u16)f2b(t - b2f(hb2));
            }
}

// ---------------------------------------------------------------------------
// C[8192,512] = act(A @ B^T + bias) (+ bf16 residual Rb) -- FF path.
// 128x64 tile, grid (8, 64), XCD-chunk swizzle. OUTMODE: 0 = fp32 (+Rb),
// 2 = bf16 hi only.
// ---------------------------------------------------------------------------
template<int RELU, int OUTMODE>
__global__ __launch_bounds__(256, 4) void mm512(
    const u16* __restrict__ Ah_g, const u16* __restrict__ Bh_g,
    const float* __restrict__ bias, const u16* __restrict__ Rb,
    float* __restrict__ outF, u16* __restrict__ outHi)
{
    __shared__ u16 Ah[128 * 72], Bh[64 * 72];
    const int tid = threadIdx.x, lane = tid & 63, w = tid >> 6;
    const int wr = (w >> 1) * 64, wc = (w & 1) * 32;
    const int ml = lane & 15, q8 = (lane >> 4) * 8, q4 = (lane >> 4) * 4;
    const int bx = blockIdx.x, by = blockIdx.y;
    const int rb = (bx << 3) | (by >> 3);
    const int cb = by & 7;
    const int row0 = rb * 128, col0 = cb * 64;
    const int sra = tid >> 1, sca = (tid & 1) * 32;
    const int srb = tid >> 2, scb = (tid & 3) * 16;

    f32x4 acc[4][2];
#pragma unroll
    for (int i = 0; i < 4; ++i)
#pragma unroll
        for (int j = 0; j < 2; ++j) acc[i][j] = {0.f, 0.f, 0.f, 0.f};

    for (int k0 = 0; k0 < DM; k0 += 64) {
        const size_t ra = (size_t)(row0 + sra) * DM + k0 + sca;
        const size_t rbo = (size_t)(col0 + srb) * DM + k0 + scb;
#pragma unroll
        for (int u = 0; u < 4; ++u)
            *(uint4*)&Ah[sra * 72 + sca + u * 8] = *(const uint4*)&Ah_g[ra + u * 8];
#pragma unroll
        for (int u = 0; u < 2; ++u)
            *(uint4*)&Bh[srb * 72 + scb + u * 8] = *(const uint4*)&Bh_g[rbo + u * 8];
        __syncthreads();
#pragma unroll
        for (int kk = 0; kk < 64; kk += 32) {
            bf16x8 a_h[4], b_h[2];
#pragma unroll
            for (int i = 0; i < 4; ++i)
                a_h[i] = *(const bf16x8*)&Ah[(wr + i * 16 + ml) * 72 + kk + q8];
#pragma unroll
            for (int j = 0; j < 2; ++j)
                b_h[j] = *(const bf16x8*)&Bh[(wc + j * 16 + ml) * 72 + kk + q8];
#pragma unroll
            for (int i = 0; i < 4; ++i)
#pragma unroll
                for (int j = 0; j < 2; ++j)
                    acc[i][j] = MFMA_B16(a_h[i], b_h[j], acc[i][j]);
        }
        __syncthreads();
    }

    float bcol[2];
#pragma unroll
    for (int j = 0; j < 2; ++j) bcol[j] = bias[col0 + wc + j * 16 + ml];
#pragma unroll
    for (int i = 0; i < 4; ++i)
#pragma unroll
        for (int j = 0; j < 2; ++j)
#pragma unroll
            for (int r = 0; r < 4; ++r) {
                int gm = row0 + wr + i * 16 + q4 + r;
                int gn = col0 + wc + j * 16 + ml;
                float t = acc[i][j][r] + bcol[j];
                if (RELU) t = fmaxf(t, 0.f);
                size_t off = (size_t)gm * DM + gn;
                if (OUTMODE == 0) {
                    if (Rb) t += b2f(Rb[off]);
                    outF[off] = t;
                } else {
                    outHi[off] = (u16)f2b(t);
                }
            }
}

// ---------------------------------------------------------------------------
// FUSED attention middle, v9 = v7 + XCD-aware block swizzle (measured:
// FETCH 105->20.6MB, dur ~200us; instruction/latency-bound). 512-thread
// blocks (8 waves), acc[8]/lane, (512,4).
// ---------------------------------------------------------------------------
__global__ __launch_bounds__(512, 4) void attn_fused(
    const u16* __restrict__ qhi, const u16* __restrict__ qlo,
    const u16* __restrict__ khi, const u16* __restrict__ klo,
    const u16* __restrict__ vhi, u16* __restrict__ ao)
{
    __shared__ u16 Qh[16 * QSTR], Ql[16 * QSTR];
    __shared__ float statS[8][16], statQ[8][16];
    __shared__ int   cntW[2][8][16];
    __shared__ float2 pbuf[16 * PCAP];
    __shared__ int   pcnt[16];
    __shared__ unsigned loU[16], hiU[16];

    const int tid = threadIdx.x, lane = tid & 63, w = tid >> 6;   // w in 0..7
    const int ml = lane & 15, quad = lane >> 4, q8 = quad * 8;
    // XCD swizzle: L = x + y*64 dispatch-linear; xcd = L&7 owns batch b=xcd.
    const int L = blockIdx.x + (blockIdx.y << 6);
    const int slot = L >> 3;
    const int hb = ((slot >> 6) << 3) | (L & 7);   // h = slot>>6, b = L&7
    const int h = hb >> 3, b = hb & 7;
    const int r0 = (slot & 63) << 4;

    // ---- stage Q (16 rows x 64 dims, hi+lo planes) ----
    if (tid < 256) {
        int t2 = tid & 127, m = t2 >> 3, k8 = (t2 & 7) * 8;
        const u16* sp = (tid < 128) ? qhi : qlo;
        u16* dst = (tid < 128) ? Qh : Ql;
        *(uint4*)&dst[m * QSTR + k8] =
            *(const uint4*)&sp[((size_t)(b * NSQ + r0 + m)) * DM + h * HDIM + k8];
    }
    if (tid < 16) pcnt[tid] = 0;
    __syncthreads();

    bf16x8 a_h0 = *(const bf16x8*)&Qh[ml * QSTR + q8];
    bf16x8 a_h1 = *(const bf16x8*)&Qh[ml * QSTR + 32 + q8];
    bf16x8 a_l0 = *(const bf16x8*)&Ql[ml * QSTR + q8];
    bf16x8 a_l1 = *(const bf16x8*)&Ql[ml * QSTR + 32 + q8];

    // ---- phase 1: scores into registers (wave w owns cols w*128..w*128+127)
    const u16* khp = khi + ((size_t)(b * NSQ + w * 128 + ml)) * DM + h * HDIM + q8;
    const u16* klp = klo + ((size_t)(b * NSQ + w * 128 + ml)) * DM + h * HDIM + q8;

    f32x4 acc[8];
#pragma unroll
    for (int t = 0; t < 8; ++t) {
        bf16x8 bh0 = *(const bf16x8*)(khp);
        bf16x8 bh1 = *(const bf16x8*)(khp + 32);
        bf16x8 bl0 = *(const bf16x8*)(klp);
        bf16x8 bl1 = *(const bf16x8*)(klp + 32);
        f32x4 a0 = {0.f, 0.f, 0.f, 0.f}, a1 = {0.f, 0.f, 0.f, 0.f};
        a0 = MFMA_B16(a_h0, bh0, a0);
        a0 = MFMA_B16(a_h1, bh1, a0);
        a0 = MFMA_B16(a_l0, bh0, a0);
        a0 = MFMA_B16(a_l1, bh1, a0);
        a1 = MFMA_B16(a_h0, bl0, a1);
        a1 = MFMA_B16(a_h1, bl1, a1);
        a1 = MFMA_B16(a_l0, bl0, a1);
        a1 = MFMA_B16(a_l1, bl1, a1);
        acc[t] = a0 + a1;
        khp += 16 * DM;
        klp += 16 * DM;
    }
    // acc[t][r] = S[row = quad*4 + r][col = w*128 + t*16 + ml]

    // ---- stats: mu/sigma per row ----
    float s1[4] = {0.f, 0.f, 0.f, 0.f}, s2[4] = {0.f, 0.f, 0.f, 0.f};
#pragma unroll
    for (int t = 0; t < 8; ++t)
#pragma unroll
        for (int r = 0; r < 4; ++r) {
            float v = acc[t][r];
            s1[r] += v;
            s2[r] = fmaf(v, v, s2[r]);
        }
#pragma unroll
    for (int off = 8; off; off >>= 1)
#pragma unroll
        for (int r = 0; r < 4; ++r) {
            s1[r] += __shfl_xor(s1[r], off);
            s2[r] += __shfl_xor(s2[r], off);
        }
    if (ml == 0)
#pragma unroll
        for (int r = 0; r < 4; ++r) {
            statS[w][quad * 4 + r] = s1[r];
            statQ[w][quad * 4 + r] = s2[r];
        }
    __syncthreads();

    // count helper: threshold-compare local scores, block-reduce via LDS.
    // (barriers are unconditional -> no divergent sync)
    auto probe_count = [&](const float* thr, int buf, int* tot) {
        int c[4] = {0, 0, 0, 0};
#pragma unroll
        for (int t = 0; t < 8; ++t)
#pragma unroll
            for (int r = 0; r < 4; ++r) c[r] += (acc[t][r] > thr[r]) ? 1 : 0;
#pragma unroll
        for (int off = 8; off; off >>= 1)
#pragma unroll
            for (int r = 0; r < 4; ++r) c[r] += __shfl_xor(c[r], off);
        if (ml == 0)
#pragma unroll
            for (int r = 0; r < 4; ++r) cntW[buf][w][quad * 4 + r] = c[r];
        __syncthreads();
#pragma unroll
        for (int r = 0; r < 4; ++r) {
            int row = quad * 4 + r;
            int tt = 0;
#pragma unroll
            for (int i = 0; i < 8; ++i) tt += cntW[buf][i][row];
            tot[r] = tt;
        }
    };

    unsigned lo_u[4], hi_u[4];
    int done = 0;
    {   // ---- peeled seeded probes (mu/sg die here, before the loop) ----
        float mu[4], sg[4];
#pragma unroll
        for (int r = 0; r < 4; ++r) {
            int row = quad * 4 + r;
            float S = 0.f, Q = 0.f;
#pragma unroll
            for (int i = 0; i < 8; ++i) { S += statS[i][row]; Q += statQ[i][row]; }
            mu[r] = S * (1.f / 1024.f);
            sg[r] = sqrtf(fmaxf(Q * (1.f / 1024.f) - mu[r] * mu[r], 0.f)) + 1e-20f;
            // Chebyshev: #{x >= mu+8s} <= 16 < 32 and #{x <= mu-8s} <= 16
            lo_u[r] = ordu(mu[r] - 8.f * sg[r]);
            hi_u[r] = ordu(mu[r] + 8.f * sg[r]);
        }
        // probe A: mu + 1.70 sg
        bool below[4];
        {
            float thr[4]; unsigned tu[4]; int tot[4];
#pragma unroll
            for (int r = 0; r < 4; ++r) { thr[r] = mu[r] + 1.70f * sg[r]; tu[r] = ordu(thr[r]); }
            probe_count(thr, 0, tot);
#pragma unroll
            for (int r = 0; r < 4; ++r) {
                below[r] = (tot[r] < TOPK);
                if (tot[r] >= TOPK) {
                    lo_u[r] = tu[r];
                    if (tot[r] <= PCAP) done |= 1 << r;
                } else hi_u[r] = tu[r];
                if (hi_u[r] - lo_u[r] <= 1u) done |= 1 << r;
            }
        }
        // probe B: mu + (below ? 1.38 : 2.15) sg, clamped into (lo,hi)
        {
            float thr[4]; unsigned tu[4]; int tot[4];
#pragma unroll
            for (int r = 0; r < 4; ++r) {
                if (!((done >> r) & 1)) {
                    float fr = mu[r] + (below[r] ? 1.38f : 2.15f) * sg[r];
                    unsigned um = ordu(fr);
                    if (um <= lo_u[r] || um >= hi_u[r]) {
                        um = lo_u[r] + ((hi_u[r] - lo_u[r]) >> 1);
                        fr = iordu(um);
                    }
                    thr[r] = fr; tu[r] = um;
                } else { tu[r] = lo_u[r]; thr[r] = iordu(lo_u[r]); }
            }
            probe_count(thr, 1, tot);
#pragma unroll
            for (int r = 0; r < 4; ++r) {
                if (!((done >> r) & 1)) {
                    if (tot[r] >= TOPK) {
                        lo_u[r] = tu[r];
                        if (tot[r] <= PCAP) done |= 1 << r;
                    } else hi_u[r] = tu[r];
                    if (hi_u[r] - lo_u[r] <= 1u) done |= 1 << r;
                }
            }
        }
    }

    // ---- uint bisect loop: only lo_u/hi_u carried ----
    for (int iter = 0; iter < 22; ++iter) {
        if (__all(done == 15)) break;
        float thr[4]; unsigned tu[4]; int tot[4];
#pragma unroll
        for (int r = 0; r < 4; ++r) {
            unsigned um = ((done >> r) & 1) ? lo_u[r]
                        : lo_u[r] + ((hi_u[r] - lo_u[r]) >> 1);
            tu[r] = um; thr[r] = iordu(um);
        }
        probe_count(thr, iter & 1, tot);
#pragma unroll
        for (int r = 0; r < 4; ++r) {
            if (!((done >> r) & 1)) {
                if (tot[r] >= TOPK) {
                    lo_u[r] = tu[r];
                    if (tot[r] <= PCAP) done |= 1 << r;    // window hit
                } else hi_u[r] = tu[r];
                if (hi_u[r] - lo_u[r] <= 1u) done |= 1 << r;
            }
        }
    }

    if (w == 0 && ml == 0)
#pragma unroll
        for (int r = 0; r < 4; ++r) {
            loU[quad * 4 + r] = lo_u[r];
            hiU[quad * 4 + r] = hi_u[r];
        }

    // ---- extraction: LDS atomic append (slot order irrelevant) ----
    {
        float lof[4];
#pragma unroll
        for (int r = 0; r < 4; ++r) lof[r] = iordu(lo_u[r]);
#pragma unroll
        for (int t = 0; t < 8; ++t)
#pragma unroll
            for (int r = 0; r < 4; ++r) {
                if (acc[t][r] > lof[r]) {
                    int row = quad * 4 + r;
                    int s = atomicAdd(&pcnt[row], 1);
                    if (s < PCAP)
                        pbuf[row * PCAP + s] =
                            make_float2(acc[t][r], __int_as_float(w * 128 + t * 16 + ml));
                }
            }
    }
    __syncthreads();

    // ---- finale per wave (rows w*2, w*2+1): micro-bisect to exact 32,
    //      tie-prune, softmax (threshold shift), compact, batched PV.
    const u16* vb = vhi + ((size_t)b * NSQ) * DM + h * HDIM + lane;
    for (int rr = 0; rr < 2; ++rr) {
        const int row = w * 2 + rr;
        int n = pcnt[row];
        if (n > PCAP) n = PCAP;
        float2 pr = (lane < n) ? pbuf[row * PCAP + lane] : make_float2(0.f, 0.f);
        float val = pr.x;
        int   col = __float_as_int(pr.y);
        unsigned uv = (lane < n) ? ordu(val) : 0u;

        // micro-bisect: value-space midpoints (uint fallback alternating)
        unsigned blo = loU[row], bhi = hiU[row];
        int it = 0;
        while (bhi - blo > 1u) {
            unsigned um;
            if (it & 1) um = blo + ((bhi - blo) >> 1);
            else {
                um = ordu(0.5f * (iordu(blo) + iordu(bhi)));
                if (um <= blo || um >= bhi) um = blo + ((bhi - blo) >> 1);
            }
            ++it;
            int c = __popcll(__ballot(uv > um));
            if (c >= TOPK) { blo = um; if (c == TOPK) break; }
            else bhi = um;
        }
        bool sel = uv > blo;
        int excess = __popcll(__ballot(sel)) - TOPK;
        while (excess > 0) {        // ties at boundary (rare): drop largest cols
            int mycol = (sel && uv == blo + 1u) ? col : -1;
            int cmx = mycol;
#pragma unroll
            for (int off = 32; off; off >>= 1) cmx = max(cmx, __shfl_xor(cmx, off));
            if (sel && mycol >= 0 && col == cmx) sel = false;
            excess--;
        }

        // softmax with threshold shift (mathematically identical to max-shift)
        float mshift = iordu(blo);
        float e = sel ? __expf(val - mshift) : 0.f;
        float s = e;
#pragma unroll
        for (int off = 32; off; off >>= 1) s += __shfl_xor(s, off);
        float p = e * (1.f / s);

        // compact selected 32 to slots 0..31 (wave-local; lgkm orders wr->rd)
        unsigned long long bm = __ballot(sel);
        int slot2 = __popcll(bm & ((1ull << lane) - 1ull));
        if (sel) pbuf[row * PCAP + slot2] = make_float2(p, __int_as_float(col));

        float accv = 0.f;
#pragma unroll
        for (int t0 = 0; t0 < TOPK; t0 += 16) {
            float pp[16]; int cc[16]; u16 vv[16];
#pragma unroll
            for (int j = 0; j < 16; ++j) {
                float2 pc = pbuf[row * PCAP + t0 + j];
                pp[j] = pc.x; cc[j] = __float_as_int(pc.y);
            }
#pragma unroll
            for (int j = 0; j < 16; ++j) vv[j] = vb[(size_t)cc[j] * DM];
#pragma unroll
            for (int j = 0; j < 16; ++j) accv = fmaf(pp[j], b2f(vv[j]), accv);
        }
        ao[((size_t)(b * NSQ + r0 + row)) * DM + h * HDIM + lane] = (u16)f2b(accv);
    }
}

// ---------------------------------------------------------------------------
// LayerNorm v2 -- ROW PER WAVE: 2048 blocks x 4 waves, each wave owns one
// full row (8 f32/lane), shuffle-only reduce, no LDS, no barriers.
// out = LN(a [+ bf16 addb]) * g + be; outputs optional fp32 / bf16-hi.
// ---------------------------------------------------------------------------
__global__ __launch_bounds__(256) void ln4(
    const float* __restrict__ a, const u16* __restrict__ addb,
    const float* __restrict__ g, const float* __restrict__ be,
    float* __restrict__ outF, u16* __restrict__ outHi)
{
    const int w = threadIdx.x >> 6, lane = threadIdx.x & 63;
    const int row = blockIdx.x * 4 + w;
    const float* ap = a + (size_t)row * DM;
    float4 v0 = ((const float4*)ap)[lane];
    float4 v1 = ((const float4*)ap)[lane + 64];
    if (addb) {
        const u16* bp = addb + (size_t)row * DM;
        ushort4 b0 = ((const ushort4*)bp)[lane];
        ushort4 b1 = ((const ushort4*)bp)[lane + 64];
        v0.x += b2f(b0.x); v0.y += b2f(b0.y); v0.z += b2f(b0.z); v0.w += b2f(b0.w);
        v1.x += b2f(b1.x); v1.y += b2f(b1.y); v1.z += b2f(b1.z); v1.w += b2f(b1.w);
    }
    float s = v0.x + v0.y + v0.z + v0.w + v1.x + v1.y + v1.z + v1.w;
    float q = v0.x * v0.x + v0.y * v0.y + v0.z * v0.z + v0.w * v0.w
            + v1.x * v1.x + v1.y * v1.y + v1.z * v1.z + v1.w * v1.w;
#pragma unroll
    for (int o = 32; o; o >>= 1) { s += __shfl_xor(s, o); q += __shfl_xor(q, o); }
    float mu = s * (1.f / DM);
    float var = q * (1.f / DM) - mu * mu;
    float rs = rsqrtf(var + 1e-5f);
    float4 g0 = ((const float4*)g)[lane],  g1v = ((const float4*)g)[lane + 64];
    float4 e0 = ((const float4*)be)[lane], e1v = ((const float4*)be)[lane + 64];
    float4 o0, o1;
    o0.x = (v0.x - mu) * rs * g0.x + e0.x;
    o0.y = (v0.y - mu) * rs * g0.y + e0.y;
    o0.z = (v0.z - mu) * rs * g0.z + e0.z;
    o0.w = (v0.w - mu) * rs * g0.w + e0.w;
    o1.x = (v1.x - mu) * rs * g1v.x + e1v.x;
    o1.y = (v1.y - mu) * rs * g1v.y + e1v.y;
    o1.z = (v1.z - mu) * rs * g1v.z + e1v.z;
    o1.w = (v1.w - mu) * rs * g1v.w + e1v.w;
    if (outF) {
        ((float4*)(outF + (size_t)row * DM))[lane] = o0;
        ((float4*)(outF + (size_t)row * DM))[lane + 64] = o1;
    }
    if (outHi) {
        ushort4 h0, h1;
        h0.x = (u16)f2b(o0.x); h0.y = (u16)f2b(o0.y);
        h0.z = (u16)f2b(o0.z); h0.w = (u16)f2b(o0.w);
        h1.x = (u16)f2b(o1.x); h1.y = (u16)f2b(o1.y);
        h1.z = (u16)f2b(o1.z); h1.w = (u16)f2b(o1.w);
        ((ushort4*)(outHi + (size_t)row * DM))[lane] = h0;
        ((ushort4*)(outHi + (size_t)row * DM))[lane + 64] = h1;
    }
}

// ---------------------------------------------------------------------------
extern "C" void kernel_launch(void* const* d_in, const int* in_sizes, int n_in,
                              void* d_out, int out_size, void* d_ws, size_t ws_size,
                              hipStream_t stream) {
    const float* src = (const float*)d_in[0];
    const float* tgt = (const float*)d_in[1];
    const float* Wq  = (const float*)d_in[2];
    const float* bq  = (const float*)d_in[3];
    const float* Wk  = (const float*)d_in[4];
    const float* bk  = (const float*)d_in[5];
    const float* Wv  = (const float*)d_in[6];
    const float* bv  = (const float*)d_in[7];
    const float* W1  = (const float*)d_in[8];
    const float* b1  = (const float*)d_in[9];
    const float* W2  = (const float*)d_in[10];
    const float* b2  = (const float*)d_in[11];
    const float* g1  = (const float*)d_in[12];
    const float* be1 = (const float*)d_in[13];
    const float* g2  = (const float*)d_in[14];
    const float* be2 = (const float*)d_in[15];

    // workspace map (MB offsets). xb (fp32 LN1 out) eliminated: FF2 residual
    // comes from xhi (bf16), saving 16.8MB write + 8.4MB read.
    const size_t WPLANE = (size_t)DM * DM;
    u16* planes = (u16*)d_ws;                    // 10 x 512 KB = 5 MB
    auto wh = [&](int i) { return planes + (size_t)i * 2 * WPLANE; };
    auto at = [&](size_t mb) { return (char*)d_ws + (mb << 20); };
    u16* Thi = (u16*)at(8);   u16* Tlo = (u16*)at(16);
    u16* Shi = (u16*)at(24);  u16* Slo = (u16*)at(32);
    u16* qhi = (u16*)at(40);  u16* qlo = (u16*)at(48);
    u16* khi = (u16*)at(56);  u16* klo = (u16*)at(64);
    u16* vhi = (u16*)at(72);
    u16* aob = (u16*)at(80);
    u16* xhi = (u16*)at(104);
    u16* hhi = (u16*)at(112);
    float* f2 = (float*)at(120);                 // 16 MB fp32

    dim3 blk(256);
    const float qscale = 0.04419417382415922f;   // 1/sqrt(512)

    wconv5<<<dim3(16, 16, 5), blk, 0, stream>>>(Wq, Wk, Wv, W1, W2, planes);
    conv2<<<dim3(4096, 2), blk, 0, stream>>>(tgt, src, Thi, Tlo, Shi, Slo);

    // fused Q/K/V projection: one dispatch, 1536 blocks
    qkv512<<<dim3(8, 64, 3), blk, 0, stream>>>(Thi, Tlo, Shi, Slo, planes,
                                               bq, bk, bv, qscale,
                                               qhi, qlo, khi, klo, vhi);

    attn_fused<<<dim3(64, 64), dim3(512), 0, stream>>>(qhi, qlo, khi, klo, vhi, aob);

    ln4<<<2048, blk, 0, stream>>>(tgt, aob, g1, be1, nullptr, xhi);
    mm512<1, 2><<<dim3(8, 64), blk, 0, stream>>>(xhi, wh(3), b1, nullptr,
                                                 nullptr, hhi);
    mm512<0, 0><<<dim3(8, 64), blk, 0, stream>>>(hhi, wh(4), b2, xhi,
                                                 f2, nullptr);
    ln4<<<2048, blk, 0, stream>>>(f2, nullptr, g2, be2, (float*)d_out, nullptr);
}

// Round 13
// 382.862 us; speedup vs baseline: 1.0274x; 1.0091x over previous
//
#include <hip/hip_runtime.h>
#include <math.h>

#define NSQ 1024
#define DM  512
#define HDIM 64
#define TOPK 32
#define QSTR 72   // LDS stride for staged Q (16B-aligned, conflict-free frags)
#define PCAP 64   // candidate buffer capacity per row (one per lane)

typedef unsigned short u16;
typedef __attribute__((ext_vector_type(8))) short bf16x8;
typedef __attribute__((ext_vector_type(4))) float f32x4;

#define MFMA_B16(A,B,C) __builtin_amdgcn_mfma_f32_16x16x32_bf16(A,B,C,0,0,0)

__device__ __forceinline__ unsigned f2b(float x) {
    unsigned u = __float_as_uint(x);
    return (u + 0x7FFFu + ((u >> 16) & 1u)) >> 16;   // RN-even to bf16 bits
}
__device__ __forceinline__ float b2f(unsigned h) { return __uint_as_float(h << 16); }
__device__ __forceinline__ unsigned ordu(float f) {
    unsigned b = __float_as_uint(f);
    return b ^ (0x80000000u | (unsigned)((int)b >> 31));  // order-preserving uint
}
__device__ __forceinline__ float iordu(unsigned u) {
    unsigned b = (u & 0x80000000u) ? (u ^ 0x80000000u) : ~u;
    return __uint_as_float(b);
}

// ---------------------------------------------------------------------------
// fp32 [8192x512] x2 -> bf16 hi/lo planes (tgt -> T*, src -> S*)
// ---------------------------------------------------------------------------
__global__ __launch_bounds__(256) void conv2(
    const float* __restrict__ tgt, const float* __restrict__ src,
    u16* __restrict__ Thi, u16* __restrict__ Tlo,
    u16* __restrict__ Shi, u16* __restrict__ Slo)
{
    const int z = blockIdx.y;
    const float* x = z ? src : tgt;
    u16* hi = z ? Shi : Thi;
    u16* lo = z ? Slo : Tlo;
    int idx = blockIdx.x * 256 + threadIdx.x;
    float4 v = ((const float4*)x)[idx];
    float f[4] = {v.x, v.y, v.z, v.w};
    ushort4 hv, lv;
    unsigned h;
    h = f2b(f[0]); hv.x = (u16)h; lv.x = (u16)f2b(f[0] - b2f(h));
    h = f2b(f[1]); hv.y = (u16)h; lv.y = (u16)f2b(f[1] - b2f(h));
    h = f2b(f[2]); hv.z = (u16)h; lv.z = (u16)f2b(f[2] - b2f(h));
    h = f2b(f[3]); hv.w = (u16)h; lv.w = (u16)f2b(f[3] - b2f(h));
    ((ushort4*)hi)[idx] = hv;
    ((ushort4*)lo)[idx] = lv;
}

// ---------------------------------------------------------------------------
// All 5 weights [512,512] -> transposed bf16 hi/lo planes, one dispatch.
// ---------------------------------------------------------------------------
__global__ __launch_bounds__(256) void wconv5(
    const float* __restrict__ Wq, const float* __restrict__ Wk,
    const float* __restrict__ Wv, const float* __restrict__ W1,
    const float* __restrict__ W2, u16* __restrict__ planes)
{
    __shared__ float T[32][33];
    const int wsel = blockIdx.z;
    const float* W = (wsel == 0) ? Wq : (wsel == 1) ? Wk : (wsel == 2) ? Wv
                   : (wsel == 3) ? W1 : W2;
    u16* thi = planes + (size_t)wsel * 2 * DM * DM;
    u16* tlo = thi + (size_t)DM * DM;
    const int tx = threadIdx.x & 31, ty = threadIdx.x >> 5;
    const int n0 = blockIdx.x * 32, k0 = blockIdx.y * 32;
#pragma unroll
    for (int p = 0; p < 4; ++p) {
        int r = ty + p * 8;
        T[r][tx] = W[(size_t)(k0 + r) * DM + n0 + tx];
    }
    __syncthreads();
#pragma unroll
    for (int p = 0; p < 4; ++p) {
        int rr = ty + p * 8;
        float val = T[tx][rr];                       // = W[k0+tx][n0+rr]
        unsigned h = f2b(val);
        size_t off = (size_t)(n0 + rr) * DM + k0 + tx;
        thi[off] = (u16)h;
        tlo[off] = (u16)f2b(val - b2f(h));
    }
}

// ---------------------------------------------------------------------------
// FUSED Q/K/V projection: one dispatch, grid (8, 64, 3). z selects
// {A-planes, B-planes, bias, scale, outputs}. All three use the 3-term
// split path. XCD-chunked swizzle. 128x64 tile, BK=64, 4 waves (2Mx2N).
// ---------------------------------------------------------------------------
__global__ __launch_bounds__(256, 4) void qkv512(
    const u16* __restrict__ Thi, const u16* __restrict__ Tlo,
    const u16* __restrict__ Shi, const u16* __restrict__ Slo,
    const u16* __restrict__ planes,
    const float* __restrict__ bq, const float* __restrict__ bk,
    const float* __restrict__ bv, float qscale,
    u16* __restrict__ qhi, u16* __restrict__ qlo,
    u16* __restrict__ khi, u16* __restrict__ klo,
    u16* __restrict__ vhi)
{
    __shared__ u16 Ah[128 * 72], Bh[64 * 72];
    __shared__ u16 Al[128 * 72], Bl[64 * 72];
    const int z = blockIdx.z;
    const size_t WPLANE = (size_t)DM * DM;
    const u16* Ah_g = z ? Shi : Thi;
    const u16* Al_g = z ? Slo : Tlo;
    const u16* Bh_g = planes + (size_t)z * 2 * WPLANE;
    const u16* Bl_g = Bh_g + WPLANE;
    const float* bias = (z == 0) ? bq : (z == 1) ? bk : bv;
    const float scale = (z == 0) ? qscale : 1.f;
    u16* oh = (z == 0) ? qhi : (z == 1) ? khi : vhi;
    u16* ol = (z == 0) ? qlo : (z == 1) ? klo : nullptr;

    const int tid = threadIdx.x, lane = tid & 63, w = tid >> 6;
    const int wr = (w >> 1) * 64, wc = (w & 1) * 32;
    const int ml = lane & 15, q8 = (lane >> 4) * 8, q4 = (lane >> 4) * 4;
    const int bx = blockIdx.x, by = blockIdx.y;
    const int rb = (bx << 3) | (by >> 3);      // row-block 0..63
    const int cb = by & 7;                     // col-block 0..7
    const int row0 = rb * 128, col0 = cb * 64;
    const int sra = tid >> 1, sca = (tid & 1) * 32;   // A: 128 rows, 2 thr/row
    const int srb = tid >> 2, scb = (tid & 3) * 16;   // B: 64 rows, 4 thr/row

    f32x4 acc[4][2];
#pragma unroll
    for (int i = 0; i < 4; ++i)
#pragma unroll
        for (int j = 0; j < 2; ++j) acc[i][j] = {0.f, 0.f, 0.f, 0.f};

    for (int k0 = 0; k0 < DM; k0 += 64) {
        const size_t ra = (size_t)(row0 + sra) * DM + k0 + sca;
        const size_t rbo = (size_t)(col0 + srb) * DM + k0 + scb;
#pragma unroll
        for (int u = 0; u < 4; ++u) {
            *(uint4*)&Ah[sra * 72 + sca + u * 8] = *(const uint4*)&Ah_g[ra + u * 8];
            *(uint4*)&Al[sra * 72 + sca + u * 8] = *(const uint4*)&Al_g[ra + u * 8];
        }
#pragma unroll
        for (int u = 0; u < 2; ++u) {
            *(uint4*)&Bh[srb * 72 + scb + u * 8] = *(const uint4*)&Bh_g[rbo + u * 8];
            *(uint4*)&Bl[srb * 72 + scb + u * 8] = *(const uint4*)&Bl_g[rbo + u * 8];
        }
        __syncthreads();
#pragma unroll
        for (int kk = 0; kk < 64; kk += 32) {
            bf16x8 a_h[4], b_h[2], a_l[4], b_l[2];
#pragma unroll
            for (int i = 0; i < 4; ++i) {
                a_h[i] = *(const bf16x8*)&Ah[(wr + i * 16 + ml) * 72 + kk + q8];
                a_l[i] = *(const bf16x8*)&Al[(wr + i * 16 + ml) * 72 + kk + q8];
            }
#pragma unroll
            for (int j = 0; j < 2; ++j) {
                b_h[j] = *(const bf16x8*)&Bh[(wc + j * 16 + ml) * 72 + kk + q8];
                b_l[j] = *(const bf16x8*)&Bl[(wc + j * 16 + ml) * 72 + kk + q8];
            }
#pragma unroll
            for (int i = 0; i < 4; ++i)
#pragma unroll
                for (int j = 0; j < 2; ++j) {
                    acc[i][j] = MFMA_B16(a_h[i], b_h[j], acc[i][j]);
                    acc[i][j] = MFMA_B16(a_h[i], b_l[j], acc[i][j]);
                    acc[i][j] = MFMA_B16(a_l[i], b_h[j], acc[i][j]);
                    // lo*lo dropped: ~2^-18 relative contribution
                }
        }
        __syncthreads();
    }

    float bcol[2];
#pragma unroll
    for (int j = 0; j < 2; ++j) bcol[j] = bias[col0 + wc + j * 16 + ml];
#pragma unroll
    for (int i = 0; i < 4; ++i)
#pragma unroll
        for (int j = 0; j < 2; ++j)
#pragma unroll
            for (int r = 0; r < 4; ++r) {
                int gm = row0 + wr + i * 16 + q4 + r;
                int gn = col0 + wc + j * 16 + ml;
                float t = (acc[i][j][r] + bcol[j]) * scale;
                size_t off = (size_t)gm * DM + gn;
                unsigned hb2 = f2b(t);
                oh[off] = (u16)hb2;
                if (ol) ol[off] = (u16)f2b(t - b2f(hb2));
            }
}

// ---------------------------------------------------------------------------
// C[8192,512] = act(A @ B^T + bias) (+ bf16 residual Rb) -- FF path.
// 128x64 tile, grid (8, 64), XCD-chunk swizzle. OUTMODE: 0 = fp32 (+Rb),
// 2 = bf16 hi only.
// ---------------------------------------------------------------------------
template<int RELU, int OUTMODE>
__global__ __launch_bounds__(256, 4) void mm512(
    const u16* __restrict__ Ah_g, const u16* __restrict__ Bh_g,
    const float* __restrict__ bias, const u16* __restrict__ Rb,
    float* __restrict__ outF, u16* __restrict__ outHi)
{
    __shared__ u16 Ah[128 * 72], Bh[64 * 72];
    const int tid = threadIdx.x, lane = tid & 63, w = tid >> 6;
    const int wr = (w >> 1) * 64, wc = (w & 1) * 32;
    const int ml = lane & 15, q8 = (lane >> 4) * 8, q4 = (lane >> 4) * 4;
    const int bx = blockIdx.x, by = blockIdx.y;
    const int rb = (bx << 3) | (by >> 3);
    const int cb = by & 7;
    const int row0 = rb * 128, col0 = cb * 64;
    const int sra = tid >> 1, sca = (tid & 1) * 32;
    const int srb = tid >> 2, scb = (tid & 3) * 16;

    f32x4 acc[4][2];
#pragma unroll
    for (int i = 0; i < 4; ++i)
#pragma unroll
        for (int j = 0; j < 2; ++j) acc[i][j] = {0.f, 0.f, 0.f, 0.f};

    for (int k0 = 0; k0 < DM; k0 += 64) {
        const size_t ra = (size_t)(row0 + sra) * DM + k0 + sca;
        const size_t rbo = (size_t)(col0 + srb) * DM + k0 + scb;
#pragma unroll
        for (int u = 0; u < 4; ++u)
            *(uint4*)&Ah[sra * 72 + sca + u * 8] = *(const uint4*)&Ah_g[ra + u * 8];
#pragma unroll
        for (int u = 0; u < 2; ++u)
            *(uint4*)&Bh[srb * 72 + scb + u * 8] = *(const uint4*)&Bh_g[rbo + u * 8];
        __syncthreads();
#pragma unroll
        for (int kk = 0; kk < 64; kk += 32) {
            bf16x8 a_h[4], b_h[2];
#pragma unroll
            for (int i = 0; i < 4; ++i)
                a_h[i] = *(const bf16x8*)&Ah[(wr + i * 16 + ml) * 72 + kk + q8];
#pragma unroll
            for (int j = 0; j < 2; ++j)
                b_h[j] = *(const bf16x8*)&Bh[(wc + j * 16 + ml) * 72 + kk + q8];
#pragma unroll
            for (int i = 0; i < 4; ++i)
#pragma unroll
                for (int j = 0; j < 2; ++j)
                    acc[i][j] = MFMA_B16(a_h[i], b_h[j], acc[i][j]);
        }
        __syncthreads();
    }

    float bcol[2];
#pragma unroll
    for (int j = 0; j < 2; ++j) bcol[j] = bias[col0 + wc + j * 16 + ml];
#pragma unroll
    for (int i = 0; i < 4; ++i)
#pragma unroll
        for (int j = 0; j < 2; ++j)
#pragma unroll
            for (int r = 0; r < 4; ++r) {
                int gm = row0 + wr + i * 16 + q4 + r;
                int gn = col0 + wc + j * 16 + ml;
                float t = acc[i][j][r] + bcol[j];
                if (RELU) t = fmaxf(t, 0.f);
                size_t off = (size_t)gm * DM + gn;
                if (OUTMODE == 0) {
                    if (Rb) t += b2f(Rb[off]);
                    outF[off] = t;
                } else {
                    outHi[off] = (u16)f2b(t);
                }
            }
}

// ---------------------------------------------------------------------------
// FUSED attention middle, v10 = v9 + (a) ll-term drop in QK^T (6 MFMA/tile,
// same 3-term policy as the GEMMs, score perturbation ~2^-18 relative),
// (b) int PV gather offsets. XCD swizzle retained (FETCH 20.6MB).
// 512-thread blocks (8 waves), acc[8]/lane, (512,4).
// ---------------------------------------------------------------------------
__global__ __launch_bounds__(512, 4) void attn_fused(
    const u16* __restrict__ qhi, const u16* __restrict__ qlo,
    const u16* __restrict__ khi, const u16* __restrict__ klo,
    const u16* __restrict__ vhi, u16* __restrict__ ao)
{
    __shared__ u16 Qh[16 * QSTR], Ql[16 * QSTR];
    __shared__ float statS[8][16], statQ[8][16];
    __shared__ int   cntW[2][8][16];
    __shared__ float2 pbuf[16 * PCAP];
    __shared__ int   pcnt[16];
    __shared__ unsigned loU[16], hiU[16];

    const int tid = threadIdx.x, lane = tid & 63, w = tid >> 6;   // w in 0..7
    const int ml = lane & 15, quad = lane >> 4, q8 = quad * 8;
    // XCD swizzle: L = x + y*64 dispatch-linear; xcd = L&7 owns batch b=xcd.
    const int L = blockIdx.x + (blockIdx.y << 6);
    const int slot = L >> 3;
    const int hb = ((slot >> 6) << 3) | (L & 7);   // h = slot>>6, b = L&7
    const int h = hb >> 3, b = hb & 7;
    const int r0 = (slot & 63) << 4;

    // ---- stage Q (16 rows x 64 dims, hi+lo planes) ----
    if (tid < 256) {
        int t2 = tid & 127, m = t2 >> 3, k8 = (t2 & 7) * 8;
        const u16* sp = (tid < 128) ? qhi : qlo;
        u16* dst = (tid < 128) ? Qh : Ql;
        *(uint4*)&dst[m * QSTR + k8] =
            *(const uint4*)&sp[((size_t)(b * NSQ + r0 + m)) * DM + h * HDIM + k8];
    }
    if (tid < 16) pcnt[tid] = 0;
    __syncthreads();

    bf16x8 a_h0 = *(const bf16x8*)&Qh[ml * QSTR + q8];
    bf16x8 a_h1 = *(const bf16x8*)&Qh[ml * QSTR + 32 + q8];
    bf16x8 a_l0 = *(const bf16x8*)&Ql[ml * QSTR + q8];
    bf16x8 a_l1 = *(const bf16x8*)&Ql[ml * QSTR + 32 + q8];

    // ---- phase 1: scores into registers (wave w owns cols w*128..w*128+127)
    const u16* khp = khi + ((size_t)(b * NSQ + w * 128 + ml)) * DM + h * HDIM + q8;
    const u16* klp = klo + ((size_t)(b * NSQ + w * 128 + ml)) * DM + h * HDIM + q8;

    f32x4 acc[8];
#pragma unroll
    for (int t = 0; t < 8; ++t) {
        bf16x8 bh0 = *(const bf16x8*)(khp);
        bf16x8 bh1 = *(const bf16x8*)(khp + 32);
        bf16x8 bl0 = *(const bf16x8*)(klp);
        bf16x8 bl1 = *(const bf16x8*)(klp + 32);
        f32x4 a0 = {0.f, 0.f, 0.f, 0.f}, a1 = {0.f, 0.f, 0.f, 0.f};
        a0 = MFMA_B16(a_h0, bh0, a0);
        a0 = MFMA_B16(a_h1, bh1, a0);
        a0 = MFMA_B16(a_l0, bh0, a0);
        a0 = MFMA_B16(a_l1, bh1, a0);
        a1 = MFMA_B16(a_h0, bl0, a1);
        a1 = MFMA_B16(a_h1, bl1, a1);
        // lo*lo terms dropped (~2^-18 relative) -- 6 MFMA/tile
        acc[t] = a0 + a1;
        khp += 16 * DM;
        klp += 16 * DM;
    }
    // acc[t][r] = S[row = quad*4 + r][col = w*128 + t*16 + ml]

    // ---- stats: mu/sigma per row ----
    float s1[4] = {0.f, 0.f, 0.f, 0.f}, s2[4] = {0.f, 0.f, 0.f, 0.f};
#pragma unroll
    for (int t = 0; t < 8; ++t)
#pragma unroll
        for (int r = 0; r < 4; ++r) {
            float v = acc[t][r];
            s1[r] += v;
            s2[r] = fmaf(v, v, s2[r]);
        }
#pragma unroll
    for (int off = 8; off; off >>= 1)
#pragma unroll
        for (int r = 0; r < 4; ++r) {
            s1[r] += __shfl_xor(s1[r], off);
            s2[r] += __shfl_xor(s2[r], off);
        }
    if (ml == 0)
#pragma unroll
        for (int r = 0; r < 4; ++r) {
            statS[w][quad * 4 + r] = s1[r];
            statQ[w][quad * 4 + r] = s2[r];
        }
    __syncthreads();

    // count helper: threshold-compare local scores, block-reduce via LDS.
    // (barriers are unconditional -> no divergent sync)
    auto probe_count = [&](const float* thr, int buf, int* tot) {
        int c[4] = {0, 0, 0, 0};
#pragma unroll
        for (int t = 0; t < 8; ++t)
#pragma unroll
            for (int r = 0; r < 4; ++r) c[r] += (acc[t][r] > thr[r]) ? 1 : 0;
#pragma unroll
        for (int off = 8; off; off >>= 1)
#pragma unroll
            for (int r = 0; r < 4; ++r) c[r] += __shfl_xor(c[r], off);
        if (ml == 0)
#pragma unroll
            for (int r = 0; r < 4; ++r) cntW[buf][w][quad * 4 + r] = c[r];
        __syncthreads();
#pragma unroll
        for (int r = 0; r < 4; ++r) {
            int row = quad * 4 + r;
            int tt = 0;
#pragma unroll
            for (int i = 0; i < 8; ++i) tt += cntW[buf][i][row];
            tot[r] = tt;
        }
    };

    unsigned lo_u[4], hi_u[4];
    int done = 0;
    {   // ---- peeled seeded probes (mu/sg die here, before the loop) ----
        float mu[4], sg[4];
#pragma unroll
        for (int r = 0; r < 4; ++r) {
            int row = quad * 4 + r;
            float S = 0.f, Q = 0.f;
#pragma unroll
            for (int i = 0; i < 8; ++i) { S += statS[i][row]; Q += statQ[i][row]; }
            mu[r] = S * (1.f / 1024.f);
            sg[r] = sqrtf(fmaxf(Q * (1.f / 1024.f) - mu[r] * mu[r], 0.f)) + 1e-20f;
            // Chebyshev: #{x >= mu+8s} <= 16 < 32 and #{x <= mu-8s} <= 16
            lo_u[r] = ordu(mu[r] - 8.f * sg[r]);
            hi_u[r] = ordu(mu[r] + 8.f * sg[r]);
        }
        // probe A: mu + 1.70 sg
        bool below[4];
        {
            float thr[4]; unsigned tu[4]; int tot[4];
#pragma unroll
            for (int r = 0; r < 4; ++r) { thr[r] = mu[r] + 1.70f * sg[r]; tu[r] = ordu(thr[r]); }
            probe_count(thr, 0, tot);
#pragma unroll
            for (int r = 0; r < 4; ++r) {
                below[r] = (tot[r] < TOPK);
                if (tot[r] >= TOPK) {
                    lo_u[r] = tu[r];
                    if (tot[r] <= PCAP) done |= 1 << r;
                } else hi_u[r] = tu[r];
                if (hi_u[r] - lo_u[r] <= 1u) done |= 1 << r;
            }
        }
        // probe B: mu + (below ? 1.38 : 2.15) sg, clamped into (lo,hi)
        {
            float thr[4]; unsigned tu[4]; int tot[4];
#pragma unroll
            for (int r = 0; r < 4; ++r) {
                if (!((done >> r) & 1)) {
                    float fr = mu[r] + (below[r] ? 1.38f : 2.15f) * sg[r];
                    unsigned um = ordu(fr);
                    if (um <= lo_u[r] || um >= hi_u[r]) {
                        um = lo_u[r] + ((hi_u[r] - lo_u[r]) >> 1);
                        fr = iordu(um);
                    }
                    thr[r] = fr; tu[r] = um;
                } else { tu[r] = lo_u[r]; thr[r] = iordu(lo_u[r]); }
            }
            probe_count(thr, 1, tot);
#pragma unroll
            for (int r = 0; r < 4; ++r) {
                if (!((done >> r) & 1)) {
                    if (tot[r] >= TOPK) {
                        lo_u[r] = tu[r];
                        if (tot[r] <= PCAP) done |= 1 << r;
                    } else hi_u[r] = tu[r];
                    if (hi_u[r] - lo_u[r] <= 1u) done |= 1 << r;
                }
            }
        }
    }

    // ---- uint bisect loop: only lo_u/hi_u carried ----
    for (int iter = 0; iter < 22; ++iter) {
        if (__all(done == 15)) break;
        float thr[4]; unsigned tu[4]; int tot[4];
#pragma unroll
        for (int r = 0; r < 4; ++r) {
            unsigned um = ((done >> r) & 1) ? lo_u[r]
                        : lo_u[r] + ((hi_u[r] - lo_u[r]) >> 1);
            tu[r] = um; thr[r] = iordu(um);
        }
        probe_count(thr, iter & 1, tot);
#pragma unroll
        for (int r = 0; r < 4; ++r) {
            if (!((done >> r) & 1)) {
                if (tot[r] >= TOPK) {
                    lo_u[r] = tu[r];
                    if (tot[r] <= PCAP) done |= 1 << r;    // window hit
                } else hi_u[r] = tu[r];
                if (hi_u[r] - lo_u[r] <= 1u) done |= 1 << r;
            }
        }
    }

    if (w == 0 && ml == 0)
#pragma unroll
        for (int r = 0; r < 4; ++r) {
            loU[quad * 4 + r] = lo_u[r];
            hiU[quad * 4 + r] = hi_u[r];
        }

    // ---- extraction: LDS atomic append (slot order irrelevant) ----
    {
        float lof[4];
#pragma unroll
        for (int r = 0; r < 4; ++r) lof[r] = iordu(lo_u[r]);
#pragma unroll
        for (int t = 0; t < 8; ++t)
#pragma unroll
            for (int r = 0; r < 4; ++r) {
                if (acc[t][r] > lof[r]) {
                    int row = quad * 4 + r;
                    int s = atomicAdd(&pcnt[row], 1);
                    if (s < PCAP)
                        pbuf[row * PCAP + s] =
                            make_float2(acc[t][r], __int_as_float(w * 128 + t * 16 + ml));
                }
            }
    }
    __syncthreads();

    // ---- finale per wave (rows w*2, w*2+1): micro-bisect to exact 32,
    //      tie-prune, softmax (threshold shift), compact, batched PV.
    const u16* vb = vhi + ((size_t)b * NSQ) * DM + h * HDIM + lane;
    for (int rr = 0; rr < 2; ++rr) {
        const int row = w * 2 + rr;
        int n = pcnt[row];
        if (n > PCAP) n = PCAP;
        float2 pr = (lane < n) ? pbuf[row * PCAP + lane] : make_float2(0.f, 0.f);
        float val = pr.x;
        int   col = __float_as_int(pr.y);
        unsigned uv = (lane < n) ? ordu(val) : 0u;

        // micro-bisect: value-space midpoints (uint fallback alternating)
        unsigned blo = loU[row], bhi = hiU[row];
        int it = 0;
        while (bhi - blo > 1u) {
            unsigned um;
            if (it & 1) um = blo + ((bhi - blo) >> 1);
            else {
                um = ordu(0.5f * (iordu(blo) + iordu(bhi)));
                if (um <= blo || um >= bhi) um = blo + ((bhi - blo) >> 1);
            }
            ++it;
            int c = __popcll(__ballot(uv > um));
            if (c >= TOPK) { blo = um; if (c == TOPK) break; }
            else bhi = um;
        }
        bool sel = uv > blo;
        int excess = __popcll(__ballot(sel)) - TOPK;
        while (excess > 0) {        // ties at boundary (rare): drop largest cols
            int mycol = (sel && uv == blo + 1u) ? col : -1;
            int cmx = mycol;
#pragma unroll
            for (int off = 32; off; off >>= 1) cmx = max(cmx, __shfl_xor(cmx, off));
            if (sel && mycol >= 0 && col == cmx) sel = false;
            excess--;
        }

        // softmax with threshold shift (mathematically identical to max-shift)
        float mshift = iordu(blo);
        float e = sel ? __expf(val - mshift) : 0.f;
        float s = e;
#pragma unroll
        for (int off = 32; off; off >>= 1) s += __shfl_xor(s, off);
        float p = e * (1.f / s);

        // compact selected 32 to slots 0..31 (wave-local; lgkm orders wr->rd)
        unsigned long long bm = __ballot(sel);
        int slot2 = __popcll(bm & ((1ull << lane) - 1ull));
        if (sel) pbuf[row * PCAP + slot2] = make_float2(p, __int_as_float(col));

        float accv = 0.f;
#pragma unroll
        for (int t0 = 0; t0 < TOPK; t0 += 16) {
            float pp[16]; int cc[16]; u16 vv[16];
#pragma unroll
            for (int j = 0; j < 16; ++j) {
                float2 pc = pbuf[row * PCAP + t0 + j];
                pp[j] = pc.x;
                cc[j] = __float_as_int(pc.y) * DM;   // int offset: fits 31 bits
            }
#pragma unroll
            for (int j = 0; j < 16; ++j) vv[j] = vb[cc[j]];
#pragma unroll
            for (int j = 0; j < 16; ++j) accv = fmaf(pp[j], b2f(vv[j]), accv);
        }
        ao[((size_t)(b * NSQ + r0 + row)) * DM + h * HDIM + lane] = (u16)f2b(accv);
    }
}

// ---------------------------------------------------------------------------
// LayerNorm v2 -- ROW PER WAVE: 2048 blocks x 4 waves, each wave owns one
// full row (8 f32/lane), shuffle-only reduce, no LDS, no barriers.
// out = LN(a [+ bf16 addb]) * g + be; outputs optional fp32 / bf16-hi.
// ---------------------------------------------------------------------------
__global__ __launch_bounds__(256) void ln4(
    const float* __restrict__ a, const u16* __restrict__ addb,
    const float* __restrict__ g, const float* __restrict__ be,
    float* __restrict__ outF, u16* __restrict__ outHi)
{
    const int w = threadIdx.x >> 6, lane = threadIdx.x & 63;
    const int row = blockIdx.x * 4 + w;
    const float* ap = a + (size_t)row * DM;
    float4 v0 = ((const float4*)ap)[lane];
    float4 v1 = ((const float4*)ap)[lane + 64];
    if (addb) {
        const u16* bp = addb + (size_t)row * DM;
        ushort4 b0 = ((const ushort4*)bp)[lane];
        ushort4 b1 = ((const ushort4*)bp)[lane + 64];
        v0.x += b2f(b0.x); v0.y += b2f(b0.y); v0.z += b2f(b0.z); v0.w += b2f(b0.w);
        v1.x += b2f(b1.x); v1.y += b2f(b1.y); v1.z += b2f(b1.z); v1.w += b2f(b1.w);
    }
    float s = v0.x + v0.y + v0.z + v0.w + v1.x + v1.y + v1.z + v1.w;
    float q = v0.x * v0.x + v0.y * v0.y + v0.z * v0.z + v0.w * v0.w
            + v1.x * v1.x + v1.y * v1.y + v1.z * v1.z + v1.w * v1.w;
#pragma unroll
    for (int o = 32; o; o >>= 1) { s += __shfl_xor(s, o); q += __shfl_xor(q, o); }
    float mu = s * (1.f / DM);
    float var = q * (1.f / DM) - mu * mu;
    float rs = rsqrtf(var + 1e-5f);
    float4 g0 = ((const float4*)g)[lane],  g1v = ((const float4*)g)[lane + 64];
    float4 e0 = ((const float4*)be)[lane], e1v = ((const float4*)be)[lane + 64];
    float4 o0, o1;
    o0.x = (v0.x - mu) * rs * g0.x + e0.x;
    o0.y = (v0.y - mu) * rs * g0.y + e0.y;
    o0.z = (v0.z - mu) * rs * g0.z + e0.z;
    o0.w = (v0.w - mu) * rs * g0.w + e0.w;
    o1.x = (v1.x - mu) * rs * g1v.x + e1v.x;
    o1.y = (v1.y - mu) * rs * g1v.y + e1v.y;
    o1.z = (v1.z - mu) * rs * g1v.z + e1v.z;
    o1.w = (v1.w - mu) * rs * g1v.w + e1v.w;
    if (outF) {
        ((float4*)(outF + (size_t)row * DM))[lane] = o0;
        ((float4*)(outF + (size_t)row * DM))[lane + 64] = o1;
    }
    if (outHi) {
        ushort4 h0, h1;
        h0.x = (u16)f2b(o0.x); h0.y = (u16)f2b(o0.y);
        h0.z = (u16)f2b(o0.z); h0.w = (u16)f2b(o0.w);
        h1.x = (u16)f2b(o1.x); h1.y = (u16)f2b(o1.y);
        h1.z = (u16)f2b(o1.z); h1.w = (u16)f2b(o1.w);
        ((ushort4*)(outHi + (size_t)row * DM))[lane] = h0;
        ((ushort4*)(outHi + (size_t)row * DM))[lane + 64] = h1;
    }
}

// ---------------------------------------------------------------------------
extern "C" void kernel_launch(void* const* d_in, const int* in_sizes, int n_in,
                              void* d_out, int out_size, void* d_ws, size_t ws_size,
                              hipStream_t stream) {
    const float* src = (const float*)d_in[0];
    const float* tgt = (const float*)d_in[1];
    const float* Wq  = (const float*)d_in[2];
    const float* bq  = (const float*)d_in[3];
    const float* Wk  = (const float*)d_in[4];
    const float* bk  = (const float*)d_in[5];
    const float* Wv  = (const float*)d_in[6];
    const float* bv  = (const float*)d_in[7];
    const float* W1  = (const float*)d_in[8];
    const float* b1  = (const float*)d_in[9];
    const float* W2  = (const float*)d_in[10];
    const float* b2  = (const float*)d_in[11];
    const float* g1  = (const float*)d_in[12];
    const float* be1 = (const float*)d_in[13];
    const float* g2  = (const float*)d_in[14];
    const float* be2 = (const float*)d_in[15];

    // workspace map (MB offsets).
    const size_t WPLANE = (size_t)DM * DM;
    u16* planes = (u16*)d_ws;                    // 10 x 512 KB = 5 MB
    auto wh = [&](int i) { return planes + (size_t)i * 2 * WPLANE; };
    auto at = [&](size_t mb) { return (char*)d_ws + (mb << 20); };
    u16* Thi = (u16*)at(8);   u16* Tlo = (u16*)at(16);
    u16* Shi = (u16*)at(24);  u16* Slo = (u16*)at(32);
    u16* qhi = (u16*)at(40);  u16* qlo = (u16*)at(48);
    u16* khi = (u16*)at(56);  u16* klo = (u16*)at(64);
    u16* vhi = (u16*)at(72);
    u16* aob = (u16*)at(80);
    u16* xhi = (u16*)at(104);
    u16* hhi = (u16*)at(112);
    float* f2 = (float*)at(120);                 // 16 MB fp32

    dim3 blk(256);
    const float qscale = 0.04419417382415922f;   // 1/sqrt(512)

    wconv5<<<dim3(16, 16, 5), blk, 0, stream>>>(Wq, Wk, Wv, W1, W2, planes);
    conv2<<<dim3(4096, 2), blk, 0, stream>>>(tgt, src, Thi, Tlo, Shi, Slo);

    // fused Q/K/V projection: one dispatch, 1536 blocks
    qkv512<<<dim3(8, 64, 3), blk, 0, stream>>>(Thi, Tlo, Shi, Slo, planes,
                                               bq, bk, bv, qscale,
                                               qhi, qlo, khi, klo, vhi);

    attn_fused<<<dim3(64, 64), dim3(512), 0, stream>>>(qhi, qlo, khi, klo, vhi, aob);

    ln4<<<2048, blk, 0, stream>>>(tgt, aob, g1, be1, nullptr, xhi);
    mm512<1, 2><<<dim3(8, 64), blk, 0, stream>>>(xhi, wh(3), b1, nullptr,
                                                 nullptr, hhi);
    mm512<0, 0><<<dim3(8, 64), blk, 0, stream>>>(hhi, wh(4), b2, xhi,
                                                 f2, nullptr);
    ln4<<<2048, blk, 0, stream>>>(f2, nullptr, g2, be2, (float*)d_out, nullptr);
}

// Round 14
// 379.015 us; speedup vs baseline: 1.0379x; 1.0102x over previous
//
#include <hip/hip_runtime.h>
#include <math.h>

#define NSQ 1024
#define DM  512
#define HDIM 64
#define TOPK 32
#define QSTR 72   // LDS stride for staged Q (16B-aligned, conflict-free frags)
#define PCAP 64   // candidate buffer capacity per row (one per lane)

typedef unsigned short u16;
typedef __attribute__((ext_vector_type(8))) short bf16x8;
typedef __attribute__((ext_vector_type(4))) float f32x4;

#define MFMA_B16(A,B,C) __builtin_amdgcn_mfma_f32_16x16x32_bf16(A,B,C,0,0,0)

__device__ __forceinline__ unsigned f2b(float x) {
    unsigned u = __float_as_uint(x);
    return (u + 0x7FFFu + ((u >> 16) & 1u)) >> 16;   // RN-even to bf16 bits
}
__device__ __forceinline__ float b2f(unsigned h) { return __uint_as_float(h << 16); }
__device__ __forceinline__ unsigned ordu(float f) {
    unsigned b = __float_as_uint(f);
    return b ^ (0x80000000u | (unsigned)((int)b >> 31));  // order-preserving uint
}
__device__ __forceinline__ float iordu(unsigned u) {
    unsigned b = (u & 0x80000000u) ? (u ^ 0x80000000u) : ~u;
    return __uint_as_float(b);
}

// ---------------------------------------------------------------------------
// fp32 [8192x512] x2 -> bf16 hi/lo planes (tgt -> T*, src -> S*)
// ---------------------------------------------------------------------------
__global__ __launch_bounds__(256) void conv2(
    const float* __restrict__ tgt, const float* __restrict__ src,
    u16* __restrict__ Thi, u16* __restrict__ Tlo,
    u16* __restrict__ Shi, u16* __restrict__ Slo)
{
    const int z = blockIdx.y;
    const float* x = z ? src : tgt;
    u16* hi = z ? Shi : Thi;
    u16* lo = z ? Slo : Tlo;
    int idx = blockIdx.x * 256 + threadIdx.x;
    float4 v = ((const float4*)x)[idx];
    float f[4] = {v.x, v.y, v.z, v.w};
    ushort4 hv, lv;
    unsigned h;
    h = f2b(f[0]); hv.x = (u16)h; lv.x = (u16)f2b(f[0] - b2f(h));
    h = f2b(f[1]); hv.y = (u16)h; lv.y = (u16)f2b(f[1] - b2f(h));
    h = f2b(f[2]); hv.z = (u16)h; lv.z = (u16)f2b(f[2] - b2f(h));
    h = f2b(f[3]); hv.w = (u16)h; lv.w = (u16)f2b(f[3] - b2f(h));
    ((ushort4*)hi)[idx] = hv;
    ((ushort4*)lo)[idx] = lv;
}

// ---------------------------------------------------------------------------
// All 5 weights [512,512] -> transposed bf16 hi/lo planes, one dispatch.
// ---------------------------------------------------------------------------
__global__ __launch_bounds__(256) void wconv5(
    const float* __restrict__ Wq, const float* __restrict__ Wk,
    const float* __restrict__ Wv, const float* __restrict__ W1,
    const float* __restrict__ W2, u16* __restrict__ planes)
{
    __shared__ float T[32][33];
    const int wsel = blockIdx.z;
    const float* W = (wsel == 0) ? Wq : (wsel == 1) ? Wk : (wsel == 2) ? Wv
                   : (wsel == 3) ? W1 : W2;
    u16* thi = planes + (size_t)wsel * 2 * DM * DM;
    u16* tlo = thi + (size_t)DM * DM;
    const int tx = threadIdx.x & 31, ty = threadIdx.x >> 5;
    const int n0 = blockIdx.x * 32, k0 = blockIdx.y * 32;
#pragma unroll
    for (int p = 0; p < 4; ++p) {
        int r = ty + p * 8;
        T[r][tx] = W[(size_t)(k0 + r) * DM + n0 + tx];
    }
    __syncthreads();
#pragma unroll
    for (int p = 0; p < 4; ++p) {
        int rr = ty + p * 8;
        float val = T[tx][rr];                       // = W[k0+tx][n0+rr]
        unsigned h = f2b(val);
        size_t off = (size_t)(n0 + rr) * DM + k0 + tx;
        thi[off] = (u16)h;
        tlo[off] = (u16)f2b(val - b2f(h));
    }
}

// ---------------------------------------------------------------------------
// FUSED Q/K/V projection: one dispatch, grid (8, 64, 3). z selects
// {A-planes, B-planes, bias, scale, outputs}. All three use the 3-term
// split path. XCD-chunked swizzle. 128x64 tile, BK=64, 4 waves (2Mx2N).
// ---------------------------------------------------------------------------
__global__ __launch_bounds__(256, 4) void qkv512(
    const u16* __restrict__ Thi, const u16* __restrict__ Tlo,
    const u16* __restrict__ Shi, const u16* __restrict__ Slo,
    const u16* __restrict__ planes,
    const float* __restrict__ bq, const float* __restrict__ bk,
    const float* __restrict__ bv, float qscale,
    u16* __restrict__ qhi, u16* __restrict__ qlo,
    u16* __restrict__ khi, u16* __restrict__ klo,
    u16* __restrict__ vhi)
{
    __shared__ u16 Ah[128 * 72], Bh[64 * 72];
    __shared__ u16 Al[128 * 72], Bl[64 * 72];
    const int z = blockIdx.z;
    const size_t WPLANE = (size_t)DM * DM;
    const u16* Ah_g = z ? Shi : Thi;
    const u16* Al_g = z ? Slo : Tlo;
    const u16* Bh_g = planes + (size_t)z * 2 * WPLANE;
    const u16* Bl_g = Bh_g + WPLANE;
    const float* bias = (z == 0) ? bq : (z == 1) ? bk : bv;
    const float scale = (z == 0) ? qscale : 1.f;
    u16* oh = (z == 0) ? qhi : (z == 1) ? khi : vhi;
    u16* ol = (z == 0) ? qlo : (z == 1) ? klo : nullptr;

    const int tid = threadIdx.x, lane = tid & 63, w = tid >> 6;
    const int wr = (w >> 1) * 64, wc = (w & 1) * 32;
    const int ml = lane & 15, q8 = (lane >> 4) * 8, q4 = (lane >> 4) * 4;
    const int bx = blockIdx.x, by = blockIdx.y;
    const int rb = (bx << 3) | (by >> 3);      // row-block 0..63
    const int cb = by & 7;                     // col-block 0..7
    const int row0 = rb * 128, col0 = cb * 64;
    const int sra = tid >> 1, sca = (tid & 1) * 32;   // A: 128 rows, 2 thr/row
    const int srb = tid >> 2, scb = (tid & 3) * 16;   // B: 64 rows, 4 thr/row

    f32x4 acc[4][2];
#pragma unroll
    for (int i = 0; i < 4; ++i)
#pragma unroll
        for (int j = 0; j < 2; ++j) acc[i][j] = {0.f, 0.f, 0.f, 0.f};

    for (int k0 = 0; k0 < DM; k0 += 64) {
        const size_t ra = (size_t)(row0 + sra) * DM + k0 + sca;
        const size_t rbo = (size_t)(col0 + srb) * DM + k0 + scb;
#pragma unroll
        for (int u = 0; u < 4; ++u) {
            *(uint4*)&Ah[sra * 72 + sca + u * 8] = *(const uint4*)&Ah_g[ra + u * 8];
            *(uint4*)&Al[sra * 72 + sca + u * 8] = *(const uint4*)&Al_g[ra + u * 8];
        }
#pragma unroll
        for (int u = 0; u < 2; ++u) {
            *(uint4*)&Bh[srb * 72 + scb + u * 8] = *(const uint4*)&Bh_g[rbo + u * 8];
            *(uint4*)&Bl[srb * 72 + scb + u * 8] = *(const uint4*)&Bl_g[rbo + u * 8];
        }
        __syncthreads();
#pragma unroll
        for (int kk = 0; kk < 64; kk += 32) {
            bf16x8 a_h[4], b_h[2], a_l[4], b_l[2];
#pragma unroll
            for (int i = 0; i < 4; ++i) {
                a_h[i] = *(const bf16x8*)&Ah[(wr + i * 16 + ml) * 72 + kk + q8];
                a_l[i] = *(const bf16x8*)&Al[(wr + i * 16 + ml) * 72 + kk + q8];
            }
#pragma unroll
            for (int j = 0; j < 2; ++j) {
                b_h[j] = *(const bf16x8*)&Bh[(wc + j * 16 + ml) * 72 + kk + q8];
                b_l[j] = *(const bf16x8*)&Bl[(wc + j * 16 + ml) * 72 + kk + q8];
            }
#pragma unroll
            for (int i = 0; i < 4; ++i)
#pragma unroll
                for (int j = 0; j < 2; ++j) {
                    acc[i][j] = MFMA_B16(a_h[i], b_h[j], acc[i][j]);
                    acc[i][j] = MFMA_B16(a_h[i], b_l[j], acc[i][j]);
                    acc[i][j] = MFMA_B16(a_l[i], b_h[j], acc[i][j]);
                    // lo*lo dropped: ~2^-18 relative contribution
                }
        }
        __syncthreads();
    }

    float bcol[2];
#pragma unroll
    for (int j = 0; j < 2; ++j) bcol[j] = bias[col0 + wc + j * 16 + ml];
#pragma unroll
    for (int i = 0; i < 4; ++i)
#pragma unroll
        for (int j = 0; j < 2; ++j)
#pragma unroll
            for (int r = 0; r < 4; ++r) {
                int gm = row0 + wr + i * 16 + q4 + r;
                int gn = col0 + wc + j * 16 + ml;
                float t = (acc[i][j][r] + bcol[j]) * scale;
                size_t off = (size_t)gm * DM + gn;
                unsigned hb2 = f2b(t);
                oh[off] = (u16)hb2;
                if (ol) ol[off] = (u16)f2b(t - b2f(hb2));
            }
}

// ---------------------------------------------------------------------------
// C[8192,512] = act(A @ B^T + bias) (+ bf16 residual Rb) -- FF path.
// 128x64 tile, grid (8, 64), XCD-chunk swizzle. OUTMODE: 0 = fp32 (+Rb),
// 2 = bf16 hi only.
// ---------------------------------------------------------------------------
template<int RELU, int OUTMODE>
__global__ __launch_bounds__(256, 4) void mm512(
    const u16* __restrict__ Ah_g, const u16* __restrict__ Bh_g,
    const float* __restrict__ bias, const u16* __restrict__ Rb,
    float* __restrict__ outF, u16* __restrict__ outHi)
{
    __shared__ u16 Ah[128 * 72], Bh[64 * 72];
    const int tid = threadIdx.x, lane = tid & 63, w = tid >> 6;
    const int wr = (w >> 1) * 64, wc = (w & 1) * 32;
    const int ml = lane & 15, q8 = (lane >> 4) * 8, q4 = (lane >> 4) * 4;
    const int bx = blockIdx.x, by = blockIdx.y;
    const int rb = (bx << 3) | (by >> 3);
    const int cb = by & 7;
    const int row0 = rb * 128, col0 = cb * 64;
    const int sra = tid >> 1, sca = (tid & 1) * 32;
    const int srb = tid >> 2, scb = (tid & 3) * 16;

    f32x4 acc[4][2];
#pragma unroll
    for (int i = 0; i < 4; ++i)
#pragma unroll
        for (int j = 0; j < 2; ++j) acc[i][j] = {0.f, 0.f, 0.f, 0.f};

    for (int k0 = 0; k0 < DM; k0 += 64) {
        const size_t ra = (size_t)(row0 + sra) * DM + k0 + sca;
        const size_t rbo = (size_t)(col0 + srb) * DM + k0 + scb;
#pragma unroll
        for (int u = 0; u < 4; ++u)
            *(uint4*)&Ah[sra * 72 + sca + u * 8] = *(const uint4*)&Ah_g[ra + u * 8];
#pragma unroll
        for (int u = 0; u < 2; ++u)
            *(uint4*)&Bh[srb * 72 + scb + u * 8] = *(const uint4*)&Bh_g[rbo + u * 8];
        __syncthreads();
#pragma unroll
        for (int kk = 0; kk < 64; kk += 32) {
            bf16x8 a_h[4], b_h[2];
#pragma unroll
            for (int i = 0; i < 4; ++i)
                a_h[i] = *(const bf16x8*)&Ah[(wr + i * 16 + ml) * 72 + kk + q8];
#pragma unroll
            for (int j = 0; j < 2; ++j)
                b_h[j] = *(const bf16x8*)&Bh[(wc + j * 16 + ml) * 72 + kk + q8];
#pragma unroll
            for (int i = 0; i < 4; ++i)
#pragma unroll
                for (int j = 0; j < 2; ++j)
                    acc[i][j] = MFMA_B16(a_h[i], b_h[j], acc[i][j]);
        }
        __syncthreads();
    }

    float bcol[2];
#pragma unroll
    for (int j = 0; j < 2; ++j) bcol[j] = bias[col0 + wc + j * 16 + ml];
#pragma unroll
    for (int i = 0; i < 4; ++i)
#pragma unroll
        for (int j = 0; j < 2; ++j)
#pragma unroll
            for (int r = 0; r < 4; ++r) {
                int gm = row0 + wr + i * 16 + q4 + r;
                int gn = col0 + wc + j * 16 + ml;
                float t = acc[i][j][r] + bcol[j];
                if (RELU) t = fmaxf(t, 0.f);
                size_t off = (size_t)gm * DM + gn;
                if (OUTMODE == 0) {
                    if (Rb) t += b2f(Rb[off]);
                    outF[off] = t;
                } else {
                    outHi[off] = (u16)f2b(t);
                }
            }
}

// ---------------------------------------------------------------------------
// FUSED attention middle, v11 = v10 + PACKED probe reduce: counts for two
// rows share one int (16-bit halves, exact: per-field max 1024); shfl reduce
// 8 ops (was 32); block-combine 4x ds_read_b128 of contiguous int2[8] (was
// 32 strided b32). Stats combine likewise via [row][w] layout float4 reads.
// Integer-exact -> selection bit-identical. XCD swizzle retained.
// ---------------------------------------------------------------------------
__global__ __launch_bounds__(512, 4) void attn_fused(
    const u16* __restrict__ qhi, const u16* __restrict__ qlo,
    const u16* __restrict__ khi, const u16* __restrict__ klo,
    const u16* __restrict__ vhi, u16* __restrict__ ao)
{
    __shared__ u16 Qh[16 * QSTR], Ql[16 * QSTR];
    __shared__ float statS[16][8], statQ[16][8];   // [row][wave]
    __shared__ int2  cntP[2][4][8];                // [buf][quad][wave]
    __shared__ float2 pbuf[16 * PCAP];
    __shared__ int   pcnt[16];
    __shared__ unsigned loU[16], hiU[16];

    const int tid = threadIdx.x, lane = tid & 63, w = tid >> 6;   // w in 0..7
    const int ml = lane & 15, quad = lane >> 4, q8 = quad * 8;
    // XCD swizzle: L = x + y*64 dispatch-linear; xcd = L&7 owns batch b=xcd.
    const int L = blockIdx.x + (blockIdx.y << 6);
    const int slot = L >> 3;
    const int hb = ((slot >> 6) << 3) | (L & 7);   // h = slot>>6, b = L&7
    const int h = hb >> 3, b = hb & 7;
    const int r0 = (slot & 63) << 4;

    // ---- stage Q (16 rows x 64 dims, hi+lo planes) ----
    if (tid < 256) {
        int t2 = tid & 127, m = t2 >> 3, k8 = (t2 & 7) * 8;
        const u16* sp = (tid < 128) ? qhi : qlo;
        u16* dst = (tid < 128) ? Qh : Ql;
        *(uint4*)&dst[m * QSTR + k8] =
            *(const uint4*)&sp[((size_t)(b * NSQ + r0 + m)) * DM + h * HDIM + k8];
    }
    if (tid < 16) pcnt[tid] = 0;
    __syncthreads();

    bf16x8 a_h0 = *(const bf16x8*)&Qh[ml * QSTR + q8];
    bf16x8 a_h1 = *(const bf16x8*)&Qh[ml * QSTR + 32 + q8];
    bf16x8 a_l0 = *(const bf16x8*)&Ql[ml * QSTR + q8];
    bf16x8 a_l1 = *(const bf16x8*)&Ql[ml * QSTR + 32 + q8];

    // ---- phase 1: scores into registers (wave w owns cols w*128..w*128+127)
    const u16* khp = khi + ((size_t)(b * NSQ + w * 128 + ml)) * DM + h * HDIM + q8;
    const u16* klp = klo + ((size_t)(b * NSQ + w * 128 + ml)) * DM + h * HDIM + q8;

    f32x4 acc[8];
#pragma unroll
    for (int t = 0; t < 8; ++t) {
        bf16x8 bh0 = *(const bf16x8*)(khp);
        bf16x8 bh1 = *(const bf16x8*)(khp + 32);
        bf16x8 bl0 = *(const bf16x8*)(klp);
        bf16x8 bl1 = *(const bf16x8*)(klp + 32);
        f32x4 a0 = {0.f, 0.f, 0.f, 0.f}, a1 = {0.f, 0.f, 0.f, 0.f};
        a0 = MFMA_B16(a_h0, bh0, a0);
        a0 = MFMA_B16(a_h1, bh1, a0);
        a0 = MFMA_B16(a_l0, bh0, a0);
        a0 = MFMA_B16(a_l1, bh1, a0);
        a1 = MFMA_B16(a_h0, bl0, a1);
        a1 = MFMA_B16(a_h1, bl1, a1);
        // lo*lo terms dropped (~2^-18 relative) -- 6 MFMA/tile
        acc[t] = a0 + a1;
        khp += 16 * DM;
        klp += 16 * DM;
    }
    // acc[t][r] = S[row = quad*4 + r][col = w*128 + t*16 + ml]

    // ---- stats: mu/sigma per row ----
    float s1[4] = {0.f, 0.f, 0.f, 0.f}, s2[4] = {0.f, 0.f, 0.f, 0.f};
#pragma unroll
    for (int t = 0; t < 8; ++t)
#pragma unroll
        for (int r = 0; r < 4; ++r) {
            float v = acc[t][r];
            s1[r] += v;
            s2[r] = fmaf(v, v, s2[r]);
        }
#pragma unroll
    for (int off = 8; off; off >>= 1)
#pragma unroll
        for (int r = 0; r < 4; ++r) {
            s1[r] += __shfl_xor(s1[r], off);
            s2[r] += __shfl_xor(s2[r], off);
        }
    if (ml == 0)
#pragma unroll
        for (int r = 0; r < 4; ++r) {
            statS[quad * 4 + r][w] = s1[r];
            statQ[quad * 4 + r][w] = s2[r];
        }
    __syncthreads();

    // count helper: packed 16-bit row-pair counts (exact; max 1024/field).
    // shfl reduce on 2 regs; block-combine via contiguous int2[8] per quad.
    auto probe_count = [&](const float* thr, int buf, int* tot) {
        int p01 = 0, p23 = 0;
#pragma unroll
        for (int t = 0; t < 8; ++t) {
            p01 += (acc[t][0] > thr[0]) ? 1 : 0;
            p01 += (acc[t][1] > thr[1]) ? 0x10000 : 0;
            p23 += (acc[t][2] > thr[2]) ? 1 : 0;
            p23 += (acc[t][3] > thr[3]) ? 0x10000 : 0;
        }
#pragma unroll
        for (int off = 8; off; off >>= 1) {
            p01 += __shfl_xor(p01, off);
            p23 += __shfl_xor(p23, off);
        }
        if (ml == 0) cntP[buf][quad][w] = make_int2(p01, p23);
        __syncthreads();
        const int4* cp = (const int4*)&cntP[buf][quad][0];
        int4 a0 = cp[0], a1 = cp[1], a2 = cp[2], a3 = cp[3];
        int s01 = a0.x + a0.z + a1.x + a1.z + a2.x + a2.z + a3.x + a3.z;
        int s23 = a0.y + a0.w + a1.y + a1.w + a2.y + a2.w + a3.y + a3.w;
        tot[0] = s01 & 0xFFFF; tot[1] = s01 >> 16;
        tot[2] = s23 & 0xFFFF; tot[3] = s23 >> 16;
    };

    unsigned lo_u[4], hi_u[4];
    int done = 0;
    {   // ---- peeled seeded probes (mu/sg die here, before the loop) ----
        float mu[4], sg[4];
#pragma unroll
        for (int r = 0; r < 4; ++r) {
            int row = quad * 4 + r;
            const float4* sp4 = (const float4*)&statS[row][0];
            const float4* qp4 = (const float4*)&statQ[row][0];
            float4 sa = sp4[0], sb = sp4[1], qa = qp4[0], qb = qp4[1];
            float S = sa.x + sa.y + sa.z + sa.w + sb.x + sb.y + sb.z + sb.w;
            float Q = qa.x + qa.y + qa.z + qa.w + qb.x + qb.y + qb.z + qb.w;
            mu[r] = S * (1.f / 1024.f);
            sg[r] = sqrtf(fmaxf(Q * (1.f / 1024.f) - mu[r] * mu[r], 0.f)) + 1e-20f;
            // Chebyshev: #{x >= mu+8s} <= 16 < 32 and #{x <= mu-8s} <= 16
            lo_u[r] = ordu(mu[r] - 8.f * sg[r]);
            hi_u[r] = ordu(mu[r] + 8.f * sg[r]);
        }
        // probe A: mu + 1.70 sg
        bool below[4];
        {
            float thr[4]; unsigned tu[4]; int tot[4];
#pragma unroll
            for (int r = 0; r < 4; ++r) { thr[r] = mu[r] + 1.70f * sg[r]; tu[r] = ordu(thr[r]); }
            probe_count(thr, 0, tot);
#pragma unroll
            for (int r = 0; r < 4; ++r) {
                below[r] = (tot[r] < TOPK);
                if (tot[r] >= TOPK) {
                    lo_u[r] = tu[r];
                    if (tot[r] <= PCAP) done |= 1 << r;
                } else hi_u[r] = tu[r];
                if (hi_u[r] - lo_u[r] <= 1u) done |= 1 << r;
            }
        }
        // probe B: mu + (below ? 1.38 : 2.15) sg, clamped into (lo,hi)
        {
            float thr[4]; unsigned tu[4]; int tot[4];
#pragma unroll
            for (int r = 0; r < 4; ++r) {
                if (!((done >> r) & 1)) {
                    float fr = mu[r] + (below[r] ? 1.38f : 2.15f) * sg[r];
                    unsigned um = ordu(fr);
                    if (um <= lo_u[r] || um >= hi_u[r]) {
                        um = lo_u[r] + ((hi_u[r] - lo_u[r]) >> 1);
                        fr = iordu(um);
                    }
                    thr[r] = fr; tu[r] = um;
                } else { tu[r] = lo_u[r]; thr[r] = iordu(lo_u[r]); }
            }
            probe_count(thr, 1, tot);
#pragma unroll
            for (int r = 0; r < 4; ++r) {
                if (!((done >> r) & 1)) {
                    if (tot[r] >= TOPK) {
                        lo_u[r] = tu[r];
                        if (tot[r] <= PCAP) done |= 1 << r;
                    } else hi_u[r] = tu[r];
                    if (hi_u[r] - lo_u[r] <= 1u) done |= 1 << r;
                }
            }
        }
    }

    // ---- uint bisect loop: only lo_u/hi_u carried ----
    for (int iter = 0; iter < 22; ++iter) {
        if (__all(done == 15)) break;
        float thr[4]; unsigned tu[4]; int tot[4];
#pragma unroll
        for (int r = 0; r < 4; ++r) {
            unsigned um = ((done >> r) & 1) ? lo_u[r]
                        : lo_u[r] + ((hi_u[r] - lo_u[r]) >> 1);
            tu[r] = um; thr[r] = iordu(um);
        }
        probe_count(thr, iter & 1, tot);
#pragma unroll
        for (int r = 0; r < 4; ++r) {
            if (!((done >> r) & 1)) {
                if (tot[r] >= TOPK) {
                    lo_u[r] = tu[r];
                    if (tot[r] <= PCAP) done |= 1 << r;    // window hit
                } else hi_u[r] = tu[r];
                if (hi_u[r] - lo_u[r] <= 1u) done |= 1 << r;
            }
        }
    }

    if (w == 0 && ml == 0)
#pragma unroll
        for (int r = 0; r < 4; ++r) {
            loU[quad * 4 + r] = lo_u[r];
            hiU[quad * 4 + r] = hi_u[r];
        }

    // ---- extraction: LDS atomic append (slot order irrelevant) ----
    {
        float lof[4];
#pragma unroll
        for (int r = 0; r < 4; ++r) lof[r] = iordu(lo_u[r]);
#pragma unroll
        for (int t = 0; t < 8; ++t)
#pragma unroll
            for (int r = 0; r < 4; ++r) {
                if (acc[t][r] > lof[r]) {
                    int row = quad * 4 + r;
                    int s = atomicAdd(&pcnt[row], 1);
                    if (s < PCAP)
                        pbuf[row * PCAP + s] =
                            make_float2(acc[t][r], __int_as_float(w * 128 + t * 16 + ml));
                }
            }
    }
    __syncthreads();

    // ---- finale per wave (rows w*2, w*2+1): micro-bisect to exact 32,
    //      tie-prune, softmax (threshold shift), compact, batched PV.
    const u16* vb = vhi + ((size_t)b * NSQ) * DM + h * HDIM + lane;
    for (int rr = 0; rr < 2; ++rr) {
        const int row = w * 2 + rr;
        int n = pcnt[row];
        if (n > PCAP) n = PCAP;
        float2 pr = (lane < n) ? pbuf[row * PCAP + lane] : make_float2(0.f, 0.f);
        float val = pr.x;
        int   col = __float_as_int(pr.y);
        unsigned uv = (lane < n) ? ordu(val) : 0u;

        // micro-bisect: value-space midpoints (uint fallback alternating)
        unsigned blo = loU[row], bhi = hiU[row];
        int it = 0;
        while (bhi - blo > 1u) {
            unsigned um;
            if (it & 1) um = blo + ((bhi - blo) >> 1);
            else {
                um = ordu(0.5f * (iordu(blo) + iordu(bhi)));
                if (um <= blo || um >= bhi) um = blo + ((bhi - blo) >> 1);
            }
            ++it;
            int c = __popcll(__ballot(uv > um));
            if (c >= TOPK) { blo = um; if (c == TOPK) break; }
            else bhi = um;
        }
        bool sel = uv > blo;
        int excess = __popcll(__ballot(sel)) - TOPK;
        while (excess > 0) {        // ties at boundary (rare): drop largest cols
            int mycol = (sel && uv == blo + 1u) ? col : -1;
            int cmx = mycol;
#pragma unroll
            for (int off = 32; off; off >>= 1) cmx = max(cmx, __shfl_xor(cmx, off));
            if (sel && mycol >= 0 && col == cmx) sel = false;
            excess--;
        }

        // softmax with threshold shift (mathematically identical to max-shift)
        float mshift = iordu(blo);
        float e = sel ? __expf(val - mshift) : 0.f;
        float s = e;
#pragma unroll
        for (int off = 32; off; off >>= 1) s += __shfl_xor(s, off);
        float p = e * (1.f / s);

        // compact selected 32 to slots 0..31 (wave-local; lgkm orders wr->rd)
        unsigned long long bm = __ballot(sel);
        int slot2 = __popcll(bm & ((1ull << lane) - 1ull));
        if (sel) pbuf[row * PCAP + slot2] = make_float2(p, __int_as_float(col));

        float accv = 0.f;
#pragma unroll
        for (int t0 = 0; t0 < TOPK; t0 += 16) {
            float pp[16]; int cc[16]; u16 vv[16];
#pragma unroll
            for (int j = 0; j < 16; ++j) {
                float2 pc = pbuf[row * PCAP + t0 + j];
                pp[j] = pc.x;
                cc[j] = __float_as_int(pc.y) * DM;   // int offset: fits 31 bits
            }
#pragma unroll
            for (int j = 0; j < 16; ++j) vv[j] = vb[cc[j]];
#pragma unroll
            for (int j = 0; j < 16; ++j) accv = fmaf(pp[j], b2f(vv[j]), accv);
        }
        ao[((size_t)(b * NSQ + r0 + row)) * DM + h * HDIM + lane] = (u16)f2b(accv);
    }
}

// ---------------------------------------------------------------------------
// LayerNorm v2 -- ROW PER WAVE: 2048 blocks x 4 waves, each wave owns one
// full row (8 f32/lane), shuffle-only reduce, no LDS, no barriers.
// out = LN(a [+ bf16 addb]) * g + be; outputs optional fp32 / bf16-hi.
// ---------------------------------------------------------------------------
__global__ __launch_bounds__(256) void ln4(
    const float* __restrict__ a, const u16* __restrict__ addb,
    const float* __restrict__ g, const float* __restrict__ be,
    float* __restrict__ outF, u16* __restrict__ outHi)
{
    const int w = threadIdx.x >> 6, lane = threadIdx.x & 63;
    const int row = blockIdx.x * 4 + w;
    const float* ap = a + (size_t)row * DM;
    float4 v0 = ((const float4*)ap)[lane];
    float4 v1 = ((const float4*)ap)[lane + 64];
    if (addb) {
        const u16* bp = addb + (size_t)row * DM;
        ushort4 b0 = ((const ushort4*)bp)[lane];
        ushort4 b1 = ((const ushort4*)bp)[lane + 64];
        v0.x += b2f(b0.x); v0.y += b2f(b0.y); v0.z += b2f(b0.z); v0.w += b2f(b0.w);
        v1.x += b2f(b1.x); v1.y += b2f(b1.y); v1.z += b2f(b1.z); v1.w += b2f(b1.w);
    }
    float s = v0.x + v0.y + v0.z + v0.w + v1.x + v1.y + v1.z + v1.w;
    float q = v0.x * v0.x + v0.y * v0.y + v0.z * v0.z + v0.w * v0.w
            + v1.x * v1.x + v1.y * v1.y + v1.z * v1.z + v1.w * v1.w;
#pragma unroll
    for (int o = 32; o; o >>= 1) { s += __shfl_xor(s, o); q += __shfl_xor(q, o); }
    float mu = s * (1.f / DM);
    float var = q * (1.f / DM) - mu * mu;
    float rs = rsqrtf(var + 1e-5f);
    float4 g0 = ((const float4*)g)[lane],  g1v = ((const float4*)g)[lane + 64];
    float4 e0 = ((const float4*)be)[lane], e1v = ((const float4*)be)[lane + 64];
    float4 o0, o1;
    o0.x = (v0.x - mu) * rs * g0.x + e0.x;
    o0.y = (v0.y - mu) * rs * g0.y + e0.y;
    o0.z = (v0.z - mu) * rs * g0.z + e0.z;
    o0.w = (v0.w - mu) * rs * g0.w + e0.w;
    o1.x = (v1.x - mu) * rs * g1v.x + e1v.x;
    o1.y = (v1.y - mu) * rs * g1v.y + e1v.y;
    o1.z = (v1.z - mu) * rs * g1v.z + e1v.z;
    o1.w = (v1.w - mu) * rs * g1v.w + e1v.w;
    if (outF) {
        ((float4*)(outF + (size_t)row * DM))[lane] = o0;
        ((float4*)(outF + (size_t)row * DM))[lane + 64] = o1;
    }
    if (outHi) {
        ushort4 h0, h1;
        h0.x = (u16)f2b(o0.x); h0.y = (u16)f2b(o0.y);
        h0.z = (u16)f2b(o0.z); h0.w = (u16)f2b(o0.w);
        h1.x = (u16)f2b(o1.x); h1.y = (u16)f2b(o1.y);
        h1.z = (u16)f2b(o1.z); h1.w = (u16)f2b(o1.w);
        ((ushort4*)(outHi + (size_t)row * DM))[lane] = h0;
        ((ushort4*)(outHi + (size_t)row * DM))[lane + 64] = h1;
    }
}

// ---------------------------------------------------------------------------
extern "C" void kernel_launch(void* const* d_in, const int* in_sizes, int n_in,
                              void* d_out, int out_size, void* d_ws, size_t ws_size,
                              hipStream_t stream) {
    const float* src = (const float*)d_in[0];
    const float* tgt = (const float*)d_in[1];
    const float* Wq  = (const float*)d_in[2];
    const float* bq  = (const float*)d_in[3];
    const float* Wk  = (const float*)d_in[4];
    const float* bk  = (const float*)d_in[5];
    const float* Wv  = (const float*)d_in[6];
    const float* bv  = (const float*)d_in[7];
    const float* W1  = (const float*)d_in[8];
    const float* b1  = (const float*)d_in[9];
    const float* W2  = (const float*)d_in[10];
    const float* b2  = (const float*)d_in[11];
    const float* g1  = (const float*)d_in[12];
    const float* be1 = (const float*)d_in[13];
    const float* g2  = (const float*)d_in[14];
    const float* be2 = (const float*)d_in[15];

    // workspace map (MB offsets).
    const size_t WPLANE = (size_t)DM * DM;
    u16* planes = (u16*)d_ws;                    // 10 x 512 KB = 5 MB
    auto wh = [&](int i) { return planes + (size_t)i * 2 * WPLANE; };
    auto at = [&](size_t mb) { return (char*)d_ws + (mb << 20); };
    u16* Thi = (u16*)at(8);   u16* Tlo = (u16*)at(16);
    u16* Shi = (u16*)at(24);  u16* Slo = (u16*)at(32);
    u16* qhi = (u16*)at(40);  u16* qlo = (u16*)at(48);
    u16* khi = (u16*)at(56);  u16* klo = (u16*)at(64);
    u16* vhi = (u16*)at(72);
    u16* aob = (u16*)at(80);
    u16* xhi = (u16*)at(104);
    u16* hhi = (u16*)at(112);
    float* f2 = (float*)at(120);                 // 16 MB fp32

    dim3 blk(256);
    const float qscale = 0.04419417382415922f;   // 1/sqrt(512)

    wconv5<<<dim3(16, 16, 5), blk, 0, stream>>>(Wq, Wk, Wv, W1, W2, planes);
    conv2<<<dim3(4096, 2), blk, 0, stream>>>(tgt, src, Thi, Tlo, Shi, Slo);

    // fused Q/K/V projection: one dispatch, 1536 blocks
    qkv512<<<dim3(8, 64, 3), blk, 0, stream>>>(Thi, Tlo, Shi, Slo, planes,
                                               bq, bk, bv, qscale,
                                               qhi, qlo, khi, klo, vhi);

    attn_fused<<<dim3(64, 64), dim3(512), 0, stream>>>(qhi, qlo, khi, klo, vhi, aob);

    ln4<<<2048, blk, 0, stream>>>(tgt, aob, g1, be1, nullptr, xhi);
    mm512<1, 2><<<dim3(8, 64), blk, 0, stream>>>(xhi, wh(3), b1, nullptr,
                                                 nullptr, hhi);
    mm512<0, 0><<<dim3(8, 64), blk, 0, stream>>>(hhi, wh(4), b2, xhi,
                                                 f2, nullptr);
    ln4<<<2048, blk, 0, stream>>>(f2, nullptr, g2, be2, (float*)d_out, nullptr);
}